// Round 2
// baseline (10965.664 us; speedup 1.0000x reference)
//
#include <hip/hip_runtime.h>

// Autoregressive LSTM on MI355X (gfx950).
// B=256, T=256, D=256, H=1024, O=256.
// Persistent 256-block kernel; weights LDS-resident; A-operands direct
// global->VGPR with deep prefetch; c-state in registers; split grid barrier.

typedef _Float16 f16x8 __attribute__((ext_vector_type(8)));
typedef _Float16 f16x4 __attribute__((ext_vector_type(4)));
typedef float f32x4 __attribute__((ext_vector_type(4)));

#define TSTEPS 256
#define HID 1024
#define OUTD 256
#define KF 1536            // D + H + O (WfullT K)
#define KA 1280            // A row: h[0..1024) | y[1024..1280)
#define NBLK 256

// workspace layout (bytes)
#define WFULLT_OFF 0ull                       // fp16 [4096][1536]  = 12,582,912
#define WDT_OFF    12582912ull                // fp16 [256][1024]   = 524,288
#define XH_OFF     13107200ull                // fp16 [256][256][256] = 33,554,432
#define A0_OFF     46661632ull                // fp16 [256][1280]   = 655,360
#define A1_OFF     47316992ull                // fp16 [256][1280]   = 655,360
#define BAR_OFF    47972352ull                // int counter
#define WS_NEEDED  47972608ull

#define LDS_SLAB_BYTES 98304                  // 32 vcols * 192 kblks * 16B
#define LDS_TOTAL (98304 + 16896)             // + zbuf [128][33] f32

__device__ __forceinline__ float sigf(float x) {
    return 1.0f / (1.0f + __expf(-x));
}
__device__ __forceinline__ float tanhfast(float x) {
    return 1.0f - 2.0f / (__expf(2.0f * x) + 1.0f);
}

// ---- grid barrier pieces (monotonic counter, device scope) ----
__device__ __forceinline__ void gbar_full(int* cnt, int target) {
    __syncthreads();
    if (threadIdx.x == 0) {
        __hip_atomic_fetch_add(cnt, 1, __ATOMIC_RELEASE, __HIP_MEMORY_SCOPE_AGENT);
        while (__hip_atomic_load(cnt, __ATOMIC_ACQUIRE, __HIP_MEMORY_SCOPE_AGENT) < target) {
            __builtin_amdgcn_s_sleep(2);
        }
    }
    __syncthreads();
}
__device__ __forceinline__ void gbar_arrive(int* cnt) {
    __syncthreads();   // drain all threads' prior stores (compiler emits vmcnt(0) at barrier)
    if (threadIdx.x == 0)
        __hip_atomic_fetch_add(cnt, 1, __ATOMIC_RELEASE, __HIP_MEMORY_SCOPE_AGENT);
}
__device__ __forceinline__ void gbar_wait(int* cnt, int target) {
    if (threadIdx.x == 0) {
        while (__hip_atomic_load(cnt, __ATOMIC_ACQUIRE, __HIP_MEMORY_SCOPE_AGENT) < target) {
            __builtin_amdgcn_s_sleep(2);
        }
    }
    __syncthreads();
}

// ---------------- prep kernels ----------------
// WfullT[n][k]: n = gate*1024 + hcol (z-col); k<256 -> Wx_x, 256..1280 -> Wh, else Wx_y.
__global__ void prep_w(const float* __restrict__ Wx, const float* __restrict__ Wh,
                       const float* __restrict__ Wd,
                       _Float16* __restrict__ WfullT, _Float16* __restrict__ WdT) {
    int bid = blockIdx.x;
    if (bid < 4096) {
        int n = bid;
        for (int k = threadIdx.x; k < KF; k += 256) {
            float v;
            if (k < 256)       v = Wx[(size_t)k * 4096 + n];
            else if (k < 1280) v = Wh[(size_t)(k - 256) * 4096 + n];
            else               v = Wx[(size_t)(k - 1024) * 4096 + n];
            WfullT[(size_t)n * KF + k] = (_Float16)v;
        }
    } else {
        int o = bid - 4096;
        for (int k = threadIdx.x; k < HID; k += 256) {
            WdT[(size_t)o * HID + k] = (_Float16)Wd[(size_t)k * OUTD + o];
        }
    }
}

__global__ void prep_x(const float* __restrict__ x, _Float16* __restrict__ xh, int* bar) {
    size_t i0 = ((size_t)blockIdx.x * 256 + threadIdx.x) * 8;
    float4 a = *(const float4*)(x + i0);
    float4 c = *(const float4*)(x + i0 + 4);
    f16x8 v;
    v[0] = (_Float16)a.x; v[1] = (_Float16)a.y; v[2] = (_Float16)a.z; v[3] = (_Float16)a.w;
    v[4] = (_Float16)c.x; v[5] = (_Float16)c.y; v[6] = (_Float16)c.z; v[7] = (_Float16)c.w;
    *(f16x8*)(xh + i0) = v;
    if (blockIdx.x == 0 && threadIdx.x == 0) bar[0] = 0;
}

// ---------------- GEMM part: NS K-steps of 4 MFMAs, depth-8 A prefetch ----------------
template<int NS, typename AL>
__device__ __forceinline__ void gemmPart(AL&& aload, const _Float16* slab, int kbB,
                                         int rl, int kg, f32x4 (&acc)[2][2]) {
    constexpr int PFD = (NS < 8) ? NS : 8;
    f16x8 pa[PFD][2];
#pragma unroll
    for (int i = 0; i < PFD; ++i) { pa[i][0] = aload(i, 0); pa[i][1] = aload(i, 1); }
    const int sw = rl & 7;
    const _Float16* bb0 = slab + (size_t)rl * 1536;          // vcol*192 blks *8 elems
    const _Float16* bb1 = slab + (size_t)(16 + rl) * 1536;
#pragma unroll
    for (int kk = 0; kk < NS; ++kk) {
        int kblk = kbB + kk * 4 + kg;
        int idx = (kblk ^ sw) * 8;
        f16x8 b0 = *(const f16x8*)(bb0 + idx);
        f16x8 b1 = *(const f16x8*)(bb1 + idx);
        f16x8 a0 = pa[kk % PFD][0];
        f16x8 a1 = pa[kk % PFD][1];
        if (kk + PFD < NS) {
            pa[kk % PFD][0] = aload(kk + PFD, 0);
            pa[kk % PFD][1] = aload(kk + PFD, 1);
        }
        acc[0][0] = __builtin_amdgcn_mfma_f32_16x16x32_f16(a0, b0, acc[0][0], 0, 0, 0);
        acc[0][1] = __builtin_amdgcn_mfma_f32_16x16x32_f16(a0, b1, acc[0][1], 0, 0, 0);
        acc[1][0] = __builtin_amdgcn_mfma_f32_16x16x32_f16(a1, b0, acc[1][0], 0, 0, 0);
        acc[1][1] = __builtin_amdgcn_mfma_f32_16x16x32_f16(a1, b1, acc[1][1], 0, 0, 0);
    }
}

// ---------------- persistent LSTM ----------------
// Phase A mapping: rowgrp = bid>>7 (0..1) -> bat0 = rowgrp*128; colblk = bid&127 -> n0 = colblk*8.
// vcol = cc*4 + gate (cc 0..7, gate 0..3) -> 32 vcols = 2 MFMA N-tiles.
// Wave w owns rows bat0 + w*32 .. +32 (2 M-tiles).
// Phase B mapping: r0 = (bid>>4)*16, c0 = (bid&15)*16; wave w takes K slice [w*256, w*256+256).
__global__ __launch_bounds__(256, 1) void lstm_persist(
        const _Float16* __restrict__ WfullT, const _Float16* __restrict__ WdT,
        const _Float16* __restrict__ xh, const float* __restrict__ b,
        const float* __restrict__ bd,
        _Float16* __restrict__ A0, _Float16* __restrict__ A1,
        int* bar, float* __restrict__ out) {
    extern __shared__ char dynsm[];
    _Float16* slab = (_Float16*)dynsm;                 // [32 vcols][192 kblks][8]
    float* zbuf = (float*)(dynsm + LDS_SLAB_BYTES);    // [128][33] f32 (also phase-B red)

    const int tid = threadIdx.x, bid = blockIdx.x;
    const int w = tid >> 6, lane = tid & 63;
    const int rl = lane & 15, kg = lane >> 4;

    const int bat0 = (bid >> 7) << 7;
    const int n0 = (bid & 127) << 3;
    const int r0 = (bid >> 4) << 4;
    const int c0 = (bid & 15) << 4;

    // ---- init: build weight slab (swizzled), zero A0 row, load biases ----
    for (int i = tid; i < 32 * 192; i += 256) {
        int vcol = i / 192, kblk = i % 192;
        int n = (vcol & 3) * 1024 + n0 + (vcol >> 2);
        f16x8 v = *(const f16x8*)(WfullT + (size_t)n * KF + kblk * 8);
        *(f16x8*)(slab + ((size_t)vcol * 192 + (kblk ^ (vcol & 7))) * 8) = v;
    }
    {   // zero A0 row `bid` (h + y sections)
        uint4 z4; z4.x = z4.y = z4.z = z4.w = 0u;
        if (tid < 160) ((uint4*)(A0 + (size_t)bid * KA))[tid] = z4;
    }
    const int trow = tid >> 1;          // 0..127 (epilogue row)
    const int ccB = (tid & 1) * 4;      // epilogue col base (0 or 4)
    float bb[4][4];
#pragma unroll
    for (int g = 0; g < 4; ++g)
#pragma unroll
        for (int c2 = 0; c2 < 4; ++c2)
            bb[g][c2] = b[g * 1024 + n0 + ccB + c2];
    const float bdv = bd[c0 + (tid & 15)];
    float creg[4] = {0.f, 0.f, 0.f, 0.f};

    int cnt = NBLK;
    gbar_full(bar, cnt);     // init done (A0 zero, slab built)

    _Float16* Acur = A0;
    _Float16* Anext = A1;

    const size_t arow = (size_t)(bat0 + w * 32 + rl);

    for (int t = 0; t < TSTEPS; ++t) {
        f32x4 acc[2][2];
#pragma unroll
        for (int mt = 0; mt < 2; ++mt)
#pragma unroll
            for (int nt = 0; nt < 2; ++nt) {
                acc[mt][nt][0] = 0.f; acc[mt][nt][1] = 0.f;
                acc[mt][nt][2] = 0.f; acc[mt][nt][3] = 0.f;
            }

        // ---- phase A: x-part (K 0..256) + h-part (K 256..1280) ----
        {
            const _Float16* xb = xh + arow * 65536 + (size_t)t * 256 + kg * 8;
            auto loadX = [&](int kk, int mt) -> f16x8 {
                return *(const f16x8*)(xb + (size_t)mt * 16 * 65536 + kk * 32);
            };
            gemmPart<8>(loadX, slab, 0, rl, kg, acc);

            const _Float16* hb = Acur + arow * KA + kg * 8;
            auto loadH = [&](int kk, int mt) -> f16x8 {
                return *(const f16x8*)(hb + (size_t)mt * 16 * KA + kk * 32);
            };
            gemmPart<32>(loadH, slab, 32, rl, kg, acc);
        }

        // y_{t-1} ready? (arrived after previous step's phase B; hidden behind 40 K-steps)
        gbar_wait(bar, cnt);

        {   // ---- phase A: y-part (K 1280..1536) ----
            const _Float16* yb = Acur + arow * KA + 1024 + kg * 8;
            auto loadY = [&](int kk, int mt) -> f16x8 {
                return *(const f16x8*)(yb + (size_t)mt * 16 * KA + kk * 32);
            };
            gemmPart<8>(loadY, slab, 160, rl, kg, acc);
        }

        // ---- epilogue: z -> gates -> c,h (c in regs); h -> Anext ----
#pragma unroll
        for (int mt = 0; mt < 2; ++mt)
#pragma unroll
            for (int nt = 0; nt < 2; ++nt)
#pragma unroll
                for (int r = 0; r < 4; ++r) {
                    int zrow = w * 32 + mt * 16 + kg * 4 + r;
                    zbuf[zrow * 33 + nt * 16 + rl] = acc[mt][nt][r];
                }
        __syncthreads();
        {
            f16x4 hv;
#pragma unroll
            for (int c2 = 0; c2 < 4; ++c2) {
                int cc = ccB + c2;
                float zi = zbuf[trow * 33 + cc * 4 + 0];
                float zf = zbuf[trow * 33 + cc * 4 + 1];
                float zg = zbuf[trow * 33 + cc * 4 + 2];
                float zo = zbuf[trow * 33 + cc * 4 + 3];
                float iv = sigf(zi + bb[0][c2]);
                float fv = sigf(zf + bb[1][c2]);
                float gv = tanhfast(zg + bb[2][c2]);
                float ov = sigf(zo + bb[3][c2]);
                float cnew = fv * creg[c2] + iv * gv;
                creg[c2] = cnew;
                hv[c2] = (_Float16)(ov * tanhfast(cnew));
            }
            *(f16x4*)(Anext + (size_t)(bat0 + trow) * KA + n0 + ccB) = hv;
        }

        // h_t globally visible
        gbar_full(bar, cnt + NBLK);

        // ---- phase B: y = tanh(h @ Wd + bd) ----
        {
            const _Float16* hp = Anext + (size_t)(r0 + rl) * KA + (w << 8) + kg * 8;
            const _Float16* wp = WdT + (size_t)(c0 + rl) * HID + (w << 8) + kg * 8;
            f16x8 ha[8], wa[8];
#pragma unroll
            for (int it = 0; it < 8; ++it) {
                ha[it] = *(const f16x8*)(hp + it * 32);
                wa[it] = *(const f16x8*)(wp + it * 32);
            }
            f32x4 accB; accB[0] = 0.f; accB[1] = 0.f; accB[2] = 0.f; accB[3] = 0.f;
#pragma unroll
            for (int it = 0; it < 8; ++it)
                accB = __builtin_amdgcn_mfma_f32_16x16x32_f16(ha[it], wa[it], accB, 0, 0, 0);
            float* red = zbuf;
#pragma unroll
            for (int r = 0; r < 4; ++r)
                red[w * 256 + (kg * 4 + r) * 16 + rl] = accB[r];
            __syncthreads();
            int rr = tid >> 4, cc = tid & 15;
            float s = red[rr * 16 + cc] + red[256 + rr * 16 + cc] +
                      red[512 + rr * 16 + cc] + red[768 + rr * 16 + cc];
            float y = tanhfast(s + bdv);
            out[(size_t)(r0 + rr) * 65536 + (size_t)t * 256 + (c0 + cc)] = y;
            Anext[(size_t)(r0 + rr) * KA + 1024 + (c0 + cc)] = (_Float16)y;
        }

        // signal y_t written (waited on mid-next-step)
        gbar_arrive(bar);
        cnt += 2 * NBLK;

        _Float16* tmp = Acur; Acur = Anext; Anext = tmp;
    }
}

extern "C" void kernel_launch(void* const* d_in, const int* in_sizes, int n_in,
                              void* d_out, int out_size, void* d_ws, size_t ws_size,
                              hipStream_t stream) {
    const float* x  = (const float*)d_in[0];
    const float* Wx = (const float*)d_in[1];
    const float* Wh = (const float*)d_in[2];
    const float* b  = (const float*)d_in[3];
    const float* Wd = (const float*)d_in[4];
    const float* bd = (const float*)d_in[5];
    float* out = (float*)d_out;
    char* ws = (char*)d_ws;
    if (ws_size < WS_NEEDED) return;

    _Float16* WfullT = (_Float16*)(ws + WFULLT_OFF);
    _Float16* WdT    = (_Float16*)(ws + WDT_OFF);
    _Float16* xh     = (_Float16*)(ws + XH_OFF);
    _Float16* A0     = (_Float16*)(ws + A0_OFF);
    _Float16* A1     = (_Float16*)(ws + A1_OFF);
    int*      bar    = (int*)(ws + BAR_OFF);

    static int lds_set = 0;
    if (!lds_set) {   // idempotent host-side attribute; not a stream op
        hipFuncSetAttribute((const void*)lstm_persist,
                            hipFuncAttributeMaxDynamicSharedMemorySize, LDS_TOTAL);
        lds_set = 1;
    }

    prep_w<<<4352, 256, 0, stream>>>(Wx, Wh, Wd, WfullT, WdT);
    prep_x<<<8192, 256, 0, stream>>>(x, xh, bar);
    lstm_persist<<<NBLK, 256, LDS_TOTAL, stream>>>(WfullT, WdT, xh, b, bd, A0, A1, bar, out);
}

// Round 3
// 9707.365 us; speedup vs baseline: 1.1296x; 1.1296x over previous
//
#include <hip/hip_runtime.h>

// Autoregressive LSTM on MI355X (gfx950).
// B=256, T=256, D=256, H=1024, O=256.
// Persistent 256-block kernel; weights LDS-resident; A-operands direct
// global->VGPR with deep prefetch; c-state in registers.
// Round 3: distributed flag-array grid barrier (no atomic RMW chain, one
// wbl2/inv per barrier instead of per poll), WdT tile in LDS.

typedef _Float16 f16x8 __attribute__((ext_vector_type(8)));
typedef _Float16 f16x4 __attribute__((ext_vector_type(4)));
typedef float f32x4 __attribute__((ext_vector_type(4)));

#define TSTEPS 256
#define HID 1024
#define OUTD 256
#define KF 1536            // D + H + O (WfullT K)
#define KA 1280            // A row: h[0..1024) | y[1024..1280)
#define NBLK 256

// workspace layout (bytes)
#define WFULLT_OFF 0ull                       // fp16 [4096][1536]  = 12,582,912
#define WDT_OFF    12582912ull                // fp16 [256][1024]   = 524,288
#define XH_OFF     13107200ull                // fp16 [256][256][256] = 33,554,432
#define A0_OFF     46661632ull                // fp16 [256][1280]   = 655,360
#define A1_OFF     47316992ull                // fp16 [256][1280]   = 655,360
#define FLAGS_OFF  47972352ull                // int [256]
#define WS_NEEDED  47973376ull

#define LDS_SLAB_BYTES 98304                  // 32 vcols * 192 kblks * 16B
#define LDS_WDT_BYTES  32768                  // 16 cols * 128 kblks * 16B
#define LDS_ZBUF_BYTES 16896                  // [128][33] f32
#define LDS_TOTAL (LDS_SLAB_BYTES + LDS_WDT_BYTES + LDS_ZBUF_BYTES)

__device__ __forceinline__ float sigf(float x) {
    return 1.0f / (1.0f + __expf(-x));
}
__device__ __forceinline__ float tanhfast(float x) {
    return 1.0f - 2.0f / (__expf(2.0f * x) + 1.0f);
}

// ---- distributed flag barrier ----
// arrive: one release fence (wbl2) + relaxed store of epoch to own flag.
// wait: wave 0 polls 4 flags/lane with relaxed loads (no inv per poll),
//       then ONE acquire fence (inv), then block-level sync.
__device__ __forceinline__ void garrive(int* flags, int bid, int ep) {
    __syncthreads();   // all block stores drained (vmcnt0) -> in L2
    if (threadIdx.x == 0) {
        __builtin_amdgcn_fence(__ATOMIC_RELEASE, "agent");   // wbl2: L2 -> coherence point
        __hip_atomic_store(flags + bid, ep, __ATOMIC_RELAXED, __HIP_MEMORY_SCOPE_AGENT);
    }
}

__device__ __forceinline__ void gwait(int* flags, int ep) {
    if (threadIdx.x < 64) {
        int lane = threadIdx.x;
        for (;;) {
            int a0 = __hip_atomic_load(flags + lane,       __ATOMIC_RELAXED, __HIP_MEMORY_SCOPE_AGENT);
            int a1 = __hip_atomic_load(flags + lane + 64,  __ATOMIC_RELAXED, __HIP_MEMORY_SCOPE_AGENT);
            int a2 = __hip_atomic_load(flags + lane + 128, __ATOMIC_RELAXED, __HIP_MEMORY_SCOPE_AGENT);
            int a3 = __hip_atomic_load(flags + lane + 192, __ATOMIC_RELAXED, __HIP_MEMORY_SCOPE_AGENT);
            int m = min(min(a0, a1), min(a2, a3));
            if (m >= ep) break;
            __builtin_amdgcn_s_sleep(1);
        }
        __builtin_amdgcn_fence(__ATOMIC_ACQUIRE, "agent");   // single inv
    }
    __syncthreads();
}

// ---------------- prep kernels ----------------
// WfullT[n][k]: n = gate*1024 + hcol; k<256 -> Wx_x, 256..1280 -> Wh, else Wx_y.
__global__ void prep_w(const float* __restrict__ Wx, const float* __restrict__ Wh,
                       const float* __restrict__ Wd,
                       _Float16* __restrict__ WfullT, _Float16* __restrict__ WdT) {
    int bid = blockIdx.x;
    if (bid < 4096) {
        int n = bid;
        for (int k = threadIdx.x; k < KF; k += 256) {
            float v;
            if (k < 256)       v = Wx[(size_t)k * 4096 + n];
            else if (k < 1280) v = Wh[(size_t)(k - 256) * 4096 + n];
            else               v = Wx[(size_t)(k - 1024) * 4096 + n];
            WfullT[(size_t)n * KF + k] = (_Float16)v;
        }
    } else {
        int o = bid - 4096;
        for (int k = threadIdx.x; k < HID; k += 256) {
            WdT[(size_t)o * HID + k] = (_Float16)Wd[(size_t)k * OUTD + o];
        }
    }
}

__global__ void prep_x(const float* __restrict__ x, _Float16* __restrict__ xh, int* flags) {
    size_t i0 = ((size_t)blockIdx.x * 256 + threadIdx.x) * 8;
    float4 a = *(const float4*)(x + i0);
    float4 c = *(const float4*)(x + i0 + 4);
    f16x8 v;
    v[0] = (_Float16)a.x; v[1] = (_Float16)a.y; v[2] = (_Float16)a.z; v[3] = (_Float16)a.w;
    v[4] = (_Float16)c.x; v[5] = (_Float16)c.y; v[6] = (_Float16)c.z; v[7] = (_Float16)c.w;
    *(f16x8*)(xh + i0) = v;
    if (blockIdx.x == 0) flags[threadIdx.x] = 0;
}

// ---------------- GEMM part: NS K-steps of 4 MFMAs, depth-8 A prefetch ----------------
template<int NS, typename AL>
__device__ __forceinline__ void gemmPart(AL&& aload, const _Float16* slab, int kbB,
                                         int rl, int kg, f32x4 (&acc)[2][2]) {
    constexpr int PFD = (NS < 8) ? NS : 8;
    f16x8 pa[PFD][2];
#pragma unroll
    for (int i = 0; i < PFD; ++i) { pa[i][0] = aload(i, 0); pa[i][1] = aload(i, 1); }
    const int sw = rl & 7;
    const _Float16* bb0 = slab + (size_t)rl * 1536;          // vcol * 192 blks * 8 elems
    const _Float16* bb1 = slab + (size_t)(16 + rl) * 1536;
#pragma unroll
    for (int kk = 0; kk < NS; ++kk) {
        int kblk = kbB + kk * 4 + kg;
        int idx = (kblk ^ sw) * 8;
        f16x8 b0 = *(const f16x8*)(bb0 + idx);
        f16x8 b1 = *(const f16x8*)(bb1 + idx);
        f16x8 a0 = pa[kk % PFD][0];
        f16x8 a1 = pa[kk % PFD][1];
        if (kk + PFD < NS) {
            pa[kk % PFD][0] = aload(kk + PFD, 0);
            pa[kk % PFD][1] = aload(kk + PFD, 1);
        }
        acc[0][0] = __builtin_amdgcn_mfma_f32_16x16x32_f16(a0, b0, acc[0][0], 0, 0, 0);
        acc[0][1] = __builtin_amdgcn_mfma_f32_16x16x32_f16(a0, b1, acc[0][1], 0, 0, 0);
        acc[1][0] = __builtin_amdgcn_mfma_f32_16x16x32_f16(a1, b0, acc[1][0], 0, 0, 0);
        acc[1][1] = __builtin_amdgcn_mfma_f32_16x16x32_f16(a1, b1, acc[1][1], 0, 0, 0);
    }
}

// ---------------- persistent LSTM ----------------
// Phase A: bat0 = (bid>>7)*128, n0 = (bid&127)*8; vcol = cc*4+gate (32 vcols).
// Wave w owns rows bat0 + w*32 .. +32.
// Phase B: r0 = (bid>>4)*16, c0 = (bid&15)*16; wave w takes K slice [w*256, +256).
__global__ __launch_bounds__(256, 1) void lstm_persist(
        const _Float16* __restrict__ WfullT, const _Float16* __restrict__ WdT,
        const _Float16* __restrict__ xh, const float* __restrict__ b,
        const float* __restrict__ bd,
        _Float16* __restrict__ A0, _Float16* __restrict__ A1,
        int* flags, float* __restrict__ out) {
    extern __shared__ char dynsm[];
    _Float16* slab = (_Float16*)dynsm;                              // [32][192][8]
    _Float16* wdt  = (_Float16*)(dynsm + LDS_SLAB_BYTES);           // [16][128][8]
    float* zbuf = (float*)(dynsm + LDS_SLAB_BYTES + LDS_WDT_BYTES); // [128][33]

    const int tid = threadIdx.x, bid = blockIdx.x;
    const int w = tid >> 6, lane = tid & 63;
    const int rl = lane & 15, kg = lane >> 4;

    const int bat0 = (bid >> 7) << 7;
    const int n0 = (bid & 127) << 3;
    const int r0 = (bid >> 4) << 4;
    const int c0 = (bid & 15) << 4;

    // ---- init: weight slab + WdT tile (both swizzled), zero A0 row ----
    for (int i = tid; i < 32 * 192; i += 256) {
        int vcol = i / 192, kblk = i % 192;
        int n = (vcol & 3) * 1024 + n0 + (vcol >> 2);
        f16x8 v = *(const f16x8*)(WfullT + (size_t)n * KF + kblk * 8);
        *(f16x8*)(slab + ((size_t)vcol * 192 + (kblk ^ (vcol & 7))) * 8) = v;
    }
    for (int i = tid; i < 16 * 128; i += 256) {
        int wcol = i >> 7, kb = i & 127;
        f16x8 v = *(const f16x8*)(WdT + (size_t)(c0 + wcol) * HID + kb * 8);
        *(f16x8*)(wdt + ((size_t)wcol * 128 + (kb ^ (wcol & 7))) * 8) = v;
    }
    {   // zero A0 row `bid` (h + y sections)
        uint4 z4; z4.x = z4.y = z4.z = z4.w = 0u;
        if (tid < 160) ((uint4*)(A0 + (size_t)bid * KA))[tid] = z4;
    }
    const int trow = tid >> 1;          // 0..127 (epilogue row)
    const int ccB = (tid & 1) * 4;      // epilogue col base (0 or 4)
    float bb[4][4];
#pragma unroll
    for (int g = 0; g < 4; ++g)
#pragma unroll
        for (int c2 = 0; c2 < 4; ++c2)
            bb[g][c2] = b[g * 1024 + n0 + ccB + c2];
    const float bdv = bd[c0 + (tid & 15)];
    float creg[4] = {0.f, 0.f, 0.f, 0.f};

    int ep = 1;
    garrive(flags, bid, ep);
    gwait(flags, ep);

    _Float16* Acur = A0;
    _Float16* Anext = A1;

    const size_t arow = (size_t)(bat0 + w * 32 + rl);

    for (int t = 0; t < TSTEPS; ++t) {
        f32x4 acc[2][2];
#pragma unroll
        for (int mt = 0; mt < 2; ++mt)
#pragma unroll
            for (int nt = 0; nt < 2; ++nt) {
                acc[mt][nt][0] = 0.f; acc[mt][nt][1] = 0.f;
                acc[mt][nt][2] = 0.f; acc[mt][nt][3] = 0.f;
            }

        // ---- phase A: x-part (K 0..256) + h-part (K 256..1280) ----
        {
            const _Float16* xb = xh + arow * 65536 + (size_t)t * 256 + kg * 8;
            auto loadX = [&](int kk, int mt) -> f16x8 {
                return *(const f16x8*)(xb + (size_t)mt * 16 * 65536 + kk * 32);
            };
            gemmPart<8>(loadX, slab, 0, rl, kg, acc);

            const _Float16* hb = Acur + arow * KA + kg * 8;
            auto loadH = [&](int kk, int mt) -> f16x8 {
                return *(const f16x8*)(hb + (size_t)mt * 16 * KA + kk * 32);
            };
            gemmPart<32>(loadH, slab, 32, rl, kg, acc);
        }

        // y_{t-1} ready (arrive was after previous step's phase B; hidden behind GEMM)
        gwait(flags, ep);

        {   // ---- phase A: y-part (K 1280..1536) ----
            const _Float16* yb = Acur + arow * KA + 1024 + kg * 8;
            auto loadY = [&](int kk, int mt) -> f16x8 {
                return *(const f16x8*)(yb + (size_t)mt * 16 * KA + kk * 32);
            };
            gemmPart<8>(loadY, slab, 160, rl, kg, acc);
        }

        // ---- epilogue: z -> gates -> c,h (c in regs); h -> Anext ----
#pragma unroll
        for (int mt = 0; mt < 2; ++mt)
#pragma unroll
            for (int nt = 0; nt < 2; ++nt)
#pragma unroll
                for (int r = 0; r < 4; ++r) {
                    int zrow = w * 32 + mt * 16 + kg * 4 + r;
                    zbuf[zrow * 33 + nt * 16 + rl] = acc[mt][nt][r];
                }
        __syncthreads();
        {
            f16x4 hv;
#pragma unroll
            for (int c2 = 0; c2 < 4; ++c2) {
                int cc = ccB + c2;
                float zi = zbuf[trow * 33 + cc * 4 + 0];
                float zf = zbuf[trow * 33 + cc * 4 + 1];
                float zg = zbuf[trow * 33 + cc * 4 + 2];
                float zo = zbuf[trow * 33 + cc * 4 + 3];
                float iv = sigf(zi + bb[0][c2]);
                float fv = sigf(zf + bb[1][c2]);
                float gv = tanhfast(zg + bb[2][c2]);
                float ov = sigf(zo + bb[3][c2]);
                float cnew = fv * creg[c2] + iv * gv;
                creg[c2] = cnew;
                hv[c2] = (_Float16)(ov * tanhfast(cnew));
            }
            *(f16x4*)(Anext + (size_t)(bat0 + trow) * KA + n0 + ccB) = hv;
        }

        // h_t globally visible
        garrive(flags, bid, ep + 1);
        gwait(flags, ep + 1);

        // ---- phase B: y = tanh(h @ Wd + bd) ----
        {
            const _Float16* hp = Anext + (size_t)(r0 + rl) * KA + (w << 8) + kg * 8;
            f16x8 ha[8], wa[8];
#pragma unroll
            for (int it = 0; it < 8; ++it)
                ha[it] = *(const f16x8*)(hp + it * 32);
#pragma unroll
            for (int it = 0; it < 8; ++it) {
                int kb = (w << 5) + it * 4 + kg;
                wa[it] = *(const f16x8*)(wdt + ((size_t)rl * 128 + (kb ^ (rl & 7))) * 8);
            }
            f32x4 accB; accB[0] = 0.f; accB[1] = 0.f; accB[2] = 0.f; accB[3] = 0.f;
#pragma unroll
            for (int it = 0; it < 8; ++it)
                accB = __builtin_amdgcn_mfma_f32_16x16x32_f16(ha[it], wa[it], accB, 0, 0, 0);
            float* red = zbuf;
#pragma unroll
            for (int r = 0; r < 4; ++r)
                red[w * 256 + (kg * 4 + r) * 16 + rl] = accB[r];
            __syncthreads();
            int rr = tid >> 4, cc = tid & 15;
            float s = red[rr * 16 + cc] + red[256 + rr * 16 + cc] +
                      red[512 + rr * 16 + cc] + red[768 + rr * 16 + cc];
            float y = tanhfast(s + bdv);
            out[(size_t)(r0 + rr) * 65536 + (size_t)t * 256 + (c0 + cc)] = y;
            Anext[(size_t)(r0 + rr) * KA + 1024 + (c0 + cc)] = (_Float16)y;
        }

        // signal y_t written (waited on mid-next-step)
        garrive(flags, bid, ep + 2);
        ep += 2;

        _Float16* tmp = Acur; Acur = Anext; Anext = tmp;
    }
}

extern "C" void kernel_launch(void* const* d_in, const int* in_sizes, int n_in,
                              void* d_out, int out_size, void* d_ws, size_t ws_size,
                              hipStream_t stream) {
    const float* x  = (const float*)d_in[0];
    const float* Wx = (const float*)d_in[1];
    const float* Wh = (const float*)d_in[2];
    const float* b  = (const float*)d_in[3];
    const float* Wd = (const float*)d_in[4];
    const float* bd = (const float*)d_in[5];
    float* out = (float*)d_out;
    char* ws = (char*)d_ws;
    if (ws_size < WS_NEEDED) return;

    _Float16* WfullT = (_Float16*)(ws + WFULLT_OFF);
    _Float16* WdT    = (_Float16*)(ws + WDT_OFF);
    _Float16* xh     = (_Float16*)(ws + XH_OFF);
    _Float16* A0     = (_Float16*)(ws + A0_OFF);
    _Float16* A1     = (_Float16*)(ws + A1_OFF);
    int*      flags  = (int*)(ws + FLAGS_OFF);

    static int lds_set = 0;
    if (!lds_set) {   // idempotent host-side attribute; not a stream op
        hipFuncSetAttribute((const void*)lstm_persist,
                            hipFuncAttributeMaxDynamicSharedMemorySize, LDS_TOTAL);
        lds_set = 1;
    }

    prep_w<<<4352, 256, 0, stream>>>(Wx, Wh, Wd, WfullT, WdT);
    prep_x<<<8192, 256, 0, stream>>>(x, xh, flags);
    lstm_persist<<<NBLK, 256, LDS_TOTAL, stream>>>(WfullT, WdT, xh, b, bd, A0, A1, flags, out);
}

// Round 4
// 4831.950 us; speedup vs baseline: 2.2694x; 2.0090x over previous
//
#include <hip/hip_runtime.h>

// Autoregressive LSTM on MI355X (gfx950).
// B=256, T=256, D=256, H=1024, O=256.
// Persistent 256-block kernel; weights LDS-resident; fence-free steady state:
// cross-block state via sc1 write-through atomic stores + 16-slot ring buffer
// (fresh addresses -> cached reads stay coherent); acquire fence only every
// 8 steps (ring-wrap staleness); padded per-block flag barrier.

typedef _Float16 f16x8 __attribute__((ext_vector_type(8)));
typedef _Float16 f16x4 __attribute__((ext_vector_type(4)));
typedef float f32x4 __attribute__((ext_vector_type(4)));

#define TSTEPS 256
#define HID 1024
#define OUTD 256
#define KF 1536            // D + H + O (WfullT K)
#define KA 1280            // ring row: h[0..1024) | y[1024..1280)
#define NBLK 256
#define RSLOTS 16
#define SLOTE (256 * KA)   // elements per ring slot

// workspace layout (bytes)
#define RING_OFF   0ull                       // fp16 16*256*1280 = 10,485,760 (aliases WfullT)
#define WFULLT_OFF 0ull                       // fp16 [4096][1536] = 12,582,912 (init-only)
#define WDT_OFF    12582912ull                // fp16 [256][1024]  = 524,288
#define XH_OFF     13107200ull                // fp16 [256][256][256] = 33,554,432
#define FLAGS_OFF  46661632ull                // 256 flags * 64B = 16,384
#define WS_NEEDED  46678016ull

#define LDS_SLAB_BYTES 98304                  // 32 vcols * 192 kblks * 16B
#define LDS_WDT_BYTES  32768                  // 16 cols * 128 kblks * 16B
#define LDS_ZBUF_BYTES 16896                  // [128][33] f32
#define LDS_TOTAL (LDS_SLAB_BYTES + LDS_WDT_BYTES + LDS_ZBUF_BYTES)

#define AGENT __HIP_MEMORY_SCOPE_AGENT

__device__ __forceinline__ float sigf(float x) {
    return 1.0f / (1.0f + __expf(-x));
}
__device__ __forceinline__ float tanhfast(float x) {
    return 1.0f - 2.0f / (__expf(2.0f * x) + 1.0f);
}

// ---- fence-free flag barrier: flags padded to 64B lines ----
// arrive: __syncthreads (vmcnt(0) drains all sc1 data stores) + relaxed sc1
// flag store. wait: 64 lanes poll 4 padded flags each, relaxed sc1 loads.
__device__ __forceinline__ void garrive(int* flags, int bid, int ep) {
    __syncthreads();
    if (threadIdx.x == 0)
        __hip_atomic_store(flags + bid * 16, ep, __ATOMIC_RELAXED, AGENT);
}
__device__ __forceinline__ void gwait(int* flags, int ep) {
    if (threadIdx.x < 64) {
        int lane = threadIdx.x;
        for (;;) {
            int a0 = __hip_atomic_load(flags + (lane)       * 16, __ATOMIC_RELAXED, AGENT);
            int a1 = __hip_atomic_load(flags + (lane + 64)  * 16, __ATOMIC_RELAXED, AGENT);
            int a2 = __hip_atomic_load(flags + (lane + 128) * 16, __ATOMIC_RELAXED, AGENT);
            int a3 = __hip_atomic_load(flags + (lane + 192) * 16, __ATOMIC_RELAXED, AGENT);
            int m = min(min(a0, a1), min(a2, a3));
            if (m >= ep) break;
            __builtin_amdgcn_s_sleep(1);
        }
    }
    __syncthreads();
}

// ---------------- prep kernels ----------------
__global__ void prep_w(const float* __restrict__ Wx, const float* __restrict__ Wh,
                       const float* __restrict__ Wd,
                       _Float16* __restrict__ WfullT, _Float16* __restrict__ WdT) {
    int bid = blockIdx.x;
    if (bid < 4096) {
        int n = bid;
        for (int k = threadIdx.x; k < KF; k += 256) {
            float v;
            if (k < 256)       v = Wx[(size_t)k * 4096 + n];
            else if (k < 1280) v = Wh[(size_t)(k - 256) * 4096 + n];
            else               v = Wx[(size_t)(k - 1024) * 4096 + n];
            WfullT[(size_t)n * KF + k] = (_Float16)v;
        }
    } else {
        int o = bid - 4096;
        for (int k = threadIdx.x; k < HID; k += 256) {
            WdT[(size_t)o * HID + k] = (_Float16)Wd[(size_t)k * OUTD + o];
        }
    }
}

__global__ void prep_x(const float* __restrict__ x, _Float16* __restrict__ xh, int* flags) {
    size_t i0 = ((size_t)blockIdx.x * 256 + threadIdx.x) * 8;
    float4 a = *(const float4*)(x + i0);
    float4 c = *(const float4*)(x + i0 + 4);
    f16x8 v;
    v[0] = (_Float16)a.x; v[1] = (_Float16)a.y; v[2] = (_Float16)a.z; v[3] = (_Float16)a.w;
    v[4] = (_Float16)c.x; v[5] = (_Float16)c.y; v[6] = (_Float16)c.z; v[7] = (_Float16)c.w;
    *(f16x8*)(xh + i0) = v;
    if (blockIdx.x == 0)
        for (int i = threadIdx.x; i < 4096; i += 256) flags[i] = 0;
}

// ---------------- GEMM part: NS K-steps of 4 MFMAs, depth-8 A prefetch ----------------
template<int NS, typename AL>
__device__ __forceinline__ void gemmPart(AL&& aload, const _Float16* slab, int kbB,
                                         int rl, int kg, f32x4 (&acc)[2][2]) {
    constexpr int PFD = (NS < 8) ? NS : 8;
    f16x8 pa[PFD][2];
#pragma unroll
    for (int i = 0; i < PFD; ++i) { pa[i][0] = aload(i, 0); pa[i][1] = aload(i, 1); }
    const int sw = rl & 7;
    const _Float16* bb0 = slab + (size_t)rl * 1536;
    const _Float16* bb1 = slab + (size_t)(16 + rl) * 1536;
#pragma unroll
    for (int kk = 0; kk < NS; ++kk) {
        int kblk = kbB + kk * 4 + kg;
        int idx = (kblk ^ sw) * 8;
        f16x8 b0 = *(const f16x8*)(bb0 + idx);
        f16x8 b1 = *(const f16x8*)(bb1 + idx);
        f16x8 a0 = pa[kk % PFD][0];
        f16x8 a1 = pa[kk % PFD][1];
        if (kk + PFD < NS) {
            pa[kk % PFD][0] = aload(kk + PFD, 0);
            pa[kk % PFD][1] = aload(kk + PFD, 1);
        }
        acc[0][0] = __builtin_amdgcn_mfma_f32_16x16x32_f16(a0, b0, acc[0][0], 0, 0, 0);
        acc[0][1] = __builtin_amdgcn_mfma_f32_16x16x32_f16(a0, b1, acc[0][1], 0, 0, 0);
        acc[1][0] = __builtin_amdgcn_mfma_f32_16x16x32_f16(a1, b0, acc[1][0], 0, 0, 0);
        acc[1][1] = __builtin_amdgcn_mfma_f32_16x16x32_f16(a1, b1, acc[1][1], 0, 0, 0);
    }
}

// ---------------- persistent LSTM ----------------
// Phase A: bat0 = (bid>>7)*128, n0 = (bid&127)*8; wave w owns rows bat0+w*32..+32.
// Phase B: r0 = (bid>>4)*16, c0 = (bid&15)*16.
// Step t: reads ring slot (t-1)&15 (skip h/y parts at t=0), writes slot t&15.
__global__ __launch_bounds__(256, 1) void lstm_persist(
        const _Float16* __restrict__ WfullT, const _Float16* __restrict__ WdT,
        const _Float16* __restrict__ xh, const float* __restrict__ b,
        const float* __restrict__ bd,
        _Float16* __restrict__ ring,
        int* flags, float* __restrict__ out) {
    extern __shared__ char dynsm[];
    _Float16* slab = (_Float16*)dynsm;                              // [32][192][8]
    _Float16* wdt  = (_Float16*)(dynsm + LDS_SLAB_BYTES);           // [16][128][8]
    float* zbuf = (float*)(dynsm + LDS_SLAB_BYTES + LDS_WDT_BYTES); // [128][33]

    const int tid = threadIdx.x, bid = blockIdx.x;
    const int w = tid >> 6, lane = tid & 63;
    const int rl = lane & 15, kg = lane >> 4;

    const int bat0 = (bid >> 7) << 7;
    const int n0 = (bid & 127) << 3;
    const int r0 = (bid >> 4) << 4;
    const int c0 = (bid & 15) << 4;

    // ---- init: weight slab + WdT tile (swizzled) into LDS ----
    for (int i = tid; i < 32 * 192; i += 256) {
        int vcol = i / 192, kblk = i % 192;
        int n = (vcol & 3) * 1024 + n0 + (vcol >> 2);
        f16x8 v = *(const f16x8*)(WfullT + (size_t)n * KF + kblk * 8);
        *(f16x8*)(slab + ((size_t)vcol * 192 + (kblk ^ (vcol & 7))) * 8) = v;
    }
    for (int i = tid; i < 16 * 128; i += 256) {
        int wcol = i >> 7, kb = i & 127;
        f16x8 v = *(const f16x8*)(WdT + (size_t)(c0 + wcol) * HID + kb * 8);
        *(f16x8*)(wdt + ((size_t)wcol * 128 + (kb ^ (wcol & 7))) * 8) = v;
    }
    const int trow = tid >> 1;          // 0..127 (epilogue row)
    const int ccB = (tid & 1) * 4;      // epilogue col base (0 or 4)
    float bb[4][4];
#pragma unroll
    for (int g = 0; g < 4; ++g)
#pragma unroll
        for (int c2 = 0; c2 < 4; ++c2)
            bb[g][c2] = b[g * 1024 + n0 + ccB + c2];
    const float bdv = bd[c0 + (tid & 15)];
    float creg[4] = {0.f, 0.f, 0.f, 0.f};

    garrive(flags, bid, 1);     // init done (all WfullT reads complete)
    gwait(flags, 1);

    const size_t arow = (size_t)(bat0 + w * 32 + rl);

    for (int t = 0; t < TSTEPS; ++t) {
        // ring-wrap staleness fence: L1/L2 inv once per 8 steps (amortized)
        if ((t & 7) == 0)
            __builtin_amdgcn_fence(__ATOMIC_ACQUIRE, "agent");

        const _Float16* slotR = ring + (size_t)((t + RSLOTS - 1) & (RSLOTS - 1)) * SLOTE;
        _Float16* slotW = ring + (size_t)(t & (RSLOTS - 1)) * SLOTE;

        f32x4 acc[2][2];
#pragma unroll
        for (int mt = 0; mt < 2; ++mt)
#pragma unroll
            for (int nt = 0; nt < 2; ++nt) {
                acc[mt][nt][0] = 0.f; acc[mt][nt][1] = 0.f;
                acc[mt][nt][2] = 0.f; acc[mt][nt][3] = 0.f;
            }

        // ---- phase A: x-part (K 0..256) + h-part (K 256..1280) ----
        {
            const _Float16* xb = xh + arow * 65536 + (size_t)t * 256 + kg * 8;
            auto loadX = [&](int kk, int mt) -> f16x8 {
                return *(const f16x8*)(xb + (size_t)mt * 16 * 65536 + kk * 32);
            };
            gemmPart<8>(loadX, slab, 0, rl, kg, acc);

            if (t > 0) {
                const _Float16* hb = slotR + arow * KA + kg * 8;
                auto loadH = [&](int kk, int mt) -> f16x8 {
                    return *(const f16x8*)(hb + (size_t)mt * 16 * KA + kk * 32);
                };
                gemmPart<32>(loadH, slab, 32, rl, kg, acc);
            }
        }

        // y_{t-1} ready (arrived after previous step's phase B; hidden behind GEMM)
        gwait(flags, 2 * t + 1);

        if (t > 0) {   // ---- phase A: y-part (K 1280..1536) ----
            const _Float16* yb = slotR + arow * KA + 1024 + kg * 8;
            auto loadY = [&](int kk, int mt) -> f16x8 {
                return *(const f16x8*)(yb + (size_t)mt * 16 * KA + kk * 32);
            };
            gemmPart<8>(loadY, slab, 160, rl, kg, acc);
        }

        // ---- epilogue: z -> gates -> c,h (c in regs); h -> ring (sc1 stores) ----
#pragma unroll
        for (int mt = 0; mt < 2; ++mt)
#pragma unroll
            for (int nt = 0; nt < 2; ++nt)
#pragma unroll
                for (int r = 0; r < 4; ++r) {
                    int zrow = w * 32 + mt * 16 + kg * 4 + r;
                    zbuf[zrow * 33 + nt * 16 + rl] = acc[mt][nt][r];
                }
        __syncthreads();
        {
            union { f16x4 v; unsigned long long u; } hu;
#pragma unroll
            for (int c2 = 0; c2 < 4; ++c2) {
                int cc = ccB + c2;
                float zi = zbuf[trow * 33 + cc * 4 + 0];
                float zf = zbuf[trow * 33 + cc * 4 + 1];
                float zg = zbuf[trow * 33 + cc * 4 + 2];
                float zo = zbuf[trow * 33 + cc * 4 + 3];
                float iv = sigf(zi + bb[0][c2]);
                float fv = sigf(zf + bb[1][c2]);
                float gv = tanhfast(zg + bb[2][c2]);
                float ov = sigf(zo + bb[3][c2]);
                float cnew = fv * creg[c2] + iv * gv;
                creg[c2] = cnew;
                hu.v[c2] = (_Float16)(ov * tanhfast(cnew));
            }
            __hip_atomic_store(
                (unsigned long long*)(slotW + (size_t)(bat0 + trow) * KA + n0 + ccB),
                hu.u, __ATOMIC_RELAXED, AGENT);
        }

        // h_t globally visible (stores drained by garrive's __syncthreads)
        garrive(flags, bid, 2 * t + 2);
        gwait(flags, 2 * t + 2);

        // ---- phase B: y = tanh(h @ Wd + bd) ----
        {
            const _Float16* hp = slotW + (size_t)(r0 + rl) * KA + (w << 8) + kg * 8;
            f16x8 ha[8], wa[8];
#pragma unroll
            for (int it = 0; it < 8; ++it)
                ha[it] = *(const f16x8*)(hp + it * 32);
#pragma unroll
            for (int it = 0; it < 8; ++it) {
                int kb = (w << 5) + it * 4 + kg;
                wa[it] = *(const f16x8*)(wdt + ((size_t)rl * 128 + (kb ^ (rl & 7))) * 8);
            }
            f32x4 accB; accB[0] = 0.f; accB[1] = 0.f; accB[2] = 0.f; accB[3] = 0.f;
#pragma unroll
            for (int it = 0; it < 8; ++it)
                accB = __builtin_amdgcn_mfma_f32_16x16x32_f16(ha[it], wa[it], accB, 0, 0, 0);
            float* red = zbuf;
#pragma unroll
            for (int r = 0; r < 4; ++r)
                red[w * 256 + (kg * 4 + r) * 16 + rl] = accB[r];
            __syncthreads();
            int rr = tid >> 4, cc = tid & 15;
            float s = red[rr * 16 + cc] + red[256 + rr * 16 + cc] +
                      red[512 + rr * 16 + cc] + red[768 + rr * 16 + cc];
            float y = tanhfast(s + bdv);
            __hip_atomic_store(out + (size_t)(r0 + rr) * 65536 + (size_t)t * 256 + (c0 + cc),
                               y, __ATOMIC_RELAXED, AGENT);
            union { _Float16 h; unsigned short u; } cv; cv.h = (_Float16)y;
            unsigned short* ys = (unsigned short*)(zbuf + 1024);
            ys[tid] = cv.u;
            __syncthreads();
            if (tid < 64) {
                unsigned long long yv = *(const unsigned long long*)(ys + tid * 4);
                int row = r0 + (tid >> 2), colb = c0 + (tid & 3) * 4;
                __hip_atomic_store(
                    (unsigned long long*)(slotW + (size_t)row * KA + 1024 + colb),
                    yv, __ATOMIC_RELAXED, AGENT);
            }
        }

        // signal y_t written (waited on mid-next-step)
        garrive(flags, bid, 2 * t + 3);
    }
}

extern "C" void kernel_launch(void* const* d_in, const int* in_sizes, int n_in,
                              void* d_out, int out_size, void* d_ws, size_t ws_size,
                              hipStream_t stream) {
    const float* x  = (const float*)d_in[0];
    const float* Wx = (const float*)d_in[1];
    const float* Wh = (const float*)d_in[2];
    const float* b  = (const float*)d_in[3];
    const float* Wd = (const float*)d_in[4];
    const float* bd = (const float*)d_in[5];
    float* out = (float*)d_out;
    char* ws = (char*)d_ws;
    if (ws_size < WS_NEEDED) return;

    _Float16* WfullT = (_Float16*)(ws + WFULLT_OFF);
    _Float16* WdT    = (_Float16*)(ws + WDT_OFF);
    _Float16* xh     = (_Float16*)(ws + XH_OFF);
    _Float16* ring   = (_Float16*)(ws + RING_OFF);
    int*      flags  = (int*)(ws + FLAGS_OFF);

    static int lds_set = 0;
    if (!lds_set) {
        hipFuncSetAttribute((const void*)lstm_persist,
                            hipFuncAttributeMaxDynamicSharedMemorySize, LDS_TOTAL);
        lds_set = 1;
    }

    prep_w<<<4352, 256, 0, stream>>>(Wx, Wh, Wd, WfullT, WdT);
    prep_x<<<8192, 256, 0, stream>>>(x, xh, flags);
    lstm_persist<<<NBLK, 256, LDS_TOTAL, stream>>>(WfullT, WdT, xh, b, bd, ring, flags, out);
}

// Round 5
// 4259.159 us; speedup vs baseline: 2.5746x; 1.1345x over previous
//
#include <hip/hip_runtime.h>

// Autoregressive LSTM on MI355X (gfx950).
// B=256, T=256, D=256, H=1024, O=256.
// Persistent 256-block kernel; weights LDS-resident; fence-free steady state
// (sc1 write-through stores + 16-slot ring + acquire fence every 8 steps);
// two independent 128-block groups; software-pipelined step loop so both
// grid-barrier waits are hidden behind GEMM work; packed flags + sleep backoff.

typedef _Float16 f16x8 __attribute__((ext_vector_type(8)));
typedef _Float16 f16x4 __attribute__((ext_vector_type(4)));
typedef float f32x4 __attribute__((ext_vector_type(4)));

#define TSTEPS 256
#define HID 1024
#define OUTD 256
#define KF 1536            // D + H + O (WfullT K)
#define KA 1280            // ring row: h[0..1024) | y[1024..1280)
#define NBLK 256
#define RSLOTS 16
#define SLOTE (256 * KA)   // elements per ring slot

// workspace layout (bytes)
#define RING_OFF   0ull                       // fp16 16*256*1280 = 10,485,760 (aliases WfullT)
#define WFULLT_OFF 0ull                       // fp16 [4096][1536] = 12,582,912 (init-only)
#define WDT_OFF    12582912ull                // fp16 [256][1024]  = 524,288
#define XH_OFF     13107200ull                // fp16 [256][256][256] = 33,554,432
#define FLAGS_OFF  46661632ull                // hflags[256] + yflags[256], 4B packed
#define WS_NEEDED  46663680ull

#define LDS_SLAB_BYTES 98304                  // 32 vcols * 192 kblks * 16B
#define LDS_WDT_BYTES  32768                  // 16 cols * 128 kblks * 16B
#define LDS_ZBUF_BYTES 16896                  // [128][33] f32
#define LDS_TOTAL (LDS_SLAB_BYTES + LDS_WDT_BYTES + LDS_ZBUF_BYTES)

#define AGENT __HIP_MEMORY_SCOPE_AGENT

__device__ __forceinline__ float sigf(float x) {
    return 1.0f / (1.0f + __expf(-x));
}
__device__ __forceinline__ float tanhfast(float x) {
    return 1.0f - 2.0f / (__expf(2.0f * x) + 1.0f);
}

// ---- barrier pieces: packed 4B flags, sc1 relaxed ops, no fences ----
__device__ __forceinline__ void garrive(int* flags, int bid, int ep) {
    __syncthreads();   // drains vmcnt(0): all sc1 data stores are at coherence point
    if (threadIdx.x == 0)
        __hip_atomic_store(flags + bid, ep, __ATOMIC_RELAXED, AGENT);
}
// group-local wait: 128 flags starting at gbase
__device__ __forceinline__ void gwait(int* flags, int gbase, int ep) {
    if (threadIdx.x < 64) {
        int lane = threadIdx.x;
        for (;;) {
            int a0 = __hip_atomic_load(flags + gbase + lane,      __ATOMIC_RELAXED, AGENT);
            int a1 = __hip_atomic_load(flags + gbase + 64 + lane, __ATOMIC_RELAXED, AGENT);
            if (min(a0, a1) >= ep) break;
            __builtin_amdgcn_s_sleep(8);
        }
    }
    __syncthreads();
}
// full-grid wait (init only)
__device__ __forceinline__ void gwait256(int* flags, int ep) {
    if (threadIdx.x < 64) {
        int lane = threadIdx.x;
        for (;;) {
            int a0 = __hip_atomic_load(flags + lane,       __ATOMIC_RELAXED, AGENT);
            int a1 = __hip_atomic_load(flags + lane + 64,  __ATOMIC_RELAXED, AGENT);
            int a2 = __hip_atomic_load(flags + lane + 128, __ATOMIC_RELAXED, AGENT);
            int a3 = __hip_atomic_load(flags + lane + 192, __ATOMIC_RELAXED, AGENT);
            if (min(min(a0, a1), min(a2, a3)) >= ep) break;
            __builtin_amdgcn_s_sleep(8);
        }
    }
    __syncthreads();
}

// ---------------- prep kernels ----------------
__global__ void prep_w(const float* __restrict__ Wx, const float* __restrict__ Wh,
                       const float* __restrict__ Wd,
                       _Float16* __restrict__ WfullT, _Float16* __restrict__ WdT) {
    int bid = blockIdx.x;
    if (bid < 4096) {
        int n = bid;
        for (int k = threadIdx.x; k < KF; k += 256) {
            float v;
            if (k < 256)       v = Wx[(size_t)k * 4096 + n];
            else if (k < 1280) v = Wh[(size_t)(k - 256) * 4096 + n];
            else               v = Wx[(size_t)(k - 1024) * 4096 + n];
            WfullT[(size_t)n * KF + k] = (_Float16)v;
        }
    } else {
        int o = bid - 4096;
        for (int k = threadIdx.x; k < HID; k += 256) {
            WdT[(size_t)o * HID + k] = (_Float16)Wd[(size_t)k * OUTD + o];
        }
    }
}

__global__ void prep_x(const float* __restrict__ x, _Float16* __restrict__ xh, int* flags) {
    size_t i0 = ((size_t)blockIdx.x * 256 + threadIdx.x) * 8;
    float4 a = *(const float4*)(x + i0);
    float4 c = *(const float4*)(x + i0 + 4);
    f16x8 v;
    v[0] = (_Float16)a.x; v[1] = (_Float16)a.y; v[2] = (_Float16)a.z; v[3] = (_Float16)a.w;
    v[4] = (_Float16)c.x; v[5] = (_Float16)c.y; v[6] = (_Float16)c.z; v[7] = (_Float16)c.w;
    *(f16x8*)(xh + i0) = v;
    if (blockIdx.x == 0) {
        flags[threadIdx.x] = 0;
        flags[256 + threadIdx.x] = 0;
    }
}

// ---------------- GEMM part: NS K-steps of 4 MFMAs, depth-8 A prefetch ----------------
template<int NS, typename AL>
__device__ __forceinline__ void gemmPart(AL&& aload, const _Float16* slab, int kbB,
                                         int rl, int kg, f32x4 (&acc)[2][2]) {
    constexpr int PFD = (NS < 8) ? NS : 8;
    f16x8 pa[PFD][2];
#pragma unroll
    for (int i = 0; i < PFD; ++i) { pa[i][0] = aload(i, 0); pa[i][1] = aload(i, 1); }
    const int sw = rl & 7;
    const _Float16* bb0 = slab + (size_t)rl * 1536;
    const _Float16* bb1 = slab + (size_t)(16 + rl) * 1536;
#pragma unroll
    for (int kk = 0; kk < NS; ++kk) {
        int kblk = kbB + kk * 4 + kg;
        int idx = (kblk ^ sw) * 8;
        f16x8 b0 = *(const f16x8*)(bb0 + idx);
        f16x8 b1 = *(const f16x8*)(bb1 + idx);
        f16x8 a0 = pa[kk % PFD][0];
        f16x8 a1 = pa[kk % PFD][1];
        if (kk + PFD < NS) {
            pa[kk % PFD][0] = aload(kk + PFD, 0);
            pa[kk % PFD][1] = aload(kk + PFD, 1);
        }
        acc[0][0] = __builtin_amdgcn_mfma_f32_16x16x32_f16(a0, b0, acc[0][0], 0, 0, 0);
        acc[0][1] = __builtin_amdgcn_mfma_f32_16x16x32_f16(a0, b1, acc[0][1], 0, 0, 0);
        acc[1][0] = __builtin_amdgcn_mfma_f32_16x16x32_f16(a1, b0, acc[1][0], 0, 0, 0);
        acc[1][1] = __builtin_amdgcn_mfma_f32_16x16x32_f16(a1, b1, acc[1][1], 0, 0, 0);
    }
}

// ---------------- persistent LSTM ----------------
// Group g = bid>>7 (128 blocks) is fully self-contained: batch rows g*128..+128
// for phase A (bat0) and phase B (r0). Barriers are group-local.
// Step t state lives in ring slot t&15 (h written end of iter t-1, y mid iter t).
__global__ __launch_bounds__(256, 1) void lstm_persist(
        const _Float16* __restrict__ WfullT, const _Float16* __restrict__ WdT,
        const _Float16* __restrict__ xh, const float* __restrict__ b,
        const float* __restrict__ bd,
        _Float16* __restrict__ ring,
        int* flags, float* __restrict__ out) {
    extern __shared__ char dynsm[];
    _Float16* slab = (_Float16*)dynsm;                              // [32][192][8]
    _Float16* wdt  = (_Float16*)(dynsm + LDS_SLAB_BYTES);           // [16][128][8]
    float* zbuf = (float*)(dynsm + LDS_SLAB_BYTES + LDS_WDT_BYTES); // [128][33]

    const int tid = threadIdx.x, bid = blockIdx.x;
    const int w = tid >> 6, lane = tid & 63;
    const int rl = lane & 15, kg = lane >> 4;

    const int bat0 = (bid >> 7) << 7;
    const int n0 = (bid & 127) << 3;
    const int r0 = (bid >> 4) << 4;
    const int c0 = (bid & 15) << 4;
    const int gbase = bid & 128;          // group flag base

    int* hflags = flags;
    int* yflags = flags + 256;

    // ---- init: weight slab + WdT tile (swizzled) into LDS ----
    for (int i = tid; i < 32 * 192; i += 256) {
        int vcol = i / 192, kblk = i % 192;
        int n = (vcol & 3) * 1024 + n0 + (vcol >> 2);
        f16x8 v = *(const f16x8*)(WfullT + (size_t)n * KF + kblk * 8);
        *(f16x8*)(slab + ((size_t)vcol * 192 + (kblk ^ (vcol & 7))) * 8) = v;
    }
    for (int i = tid; i < 16 * 128; i += 256) {
        int wcol = i >> 7, kb = i & 127;
        f16x8 v = *(const f16x8*)(WdT + (size_t)(c0 + wcol) * HID + kb * 8);
        *(f16x8*)(wdt + ((size_t)wcol * 128 + (kb ^ (wcol & 7))) * 8) = v;
    }
    const int trow = tid >> 1;          // 0..127 (epilogue row)
    const int ccB = (tid & 1) * 4;      // epilogue col base (0 or 4)
    float bb[4][4];
#pragma unroll
    for (int g = 0; g < 4; ++g)
#pragma unroll
        for (int c2 = 0; c2 < 4; ++c2)
            bb[g][c2] = b[g * 1024 + n0 + ccB + c2];
    const float bdv = bd[c0 + (tid & 15)];
    float creg[4] = {0.f, 0.f, 0.f, 0.f};

    const size_t arow = (size_t)(bat0 + w * 32 + rl);

    // epilogue: acc(z) -> gates -> c,h; h -> slotW (sc1 write-through)
    auto epilogue = [&](f32x4 (&A)[2][2], _Float16* slotW) {
#pragma unroll
        for (int mt = 0; mt < 2; ++mt)
#pragma unroll
            for (int nt = 0; nt < 2; ++nt)
#pragma unroll
                for (int r = 0; r < 4; ++r) {
                    int zrow = w * 32 + mt * 16 + kg * 4 + r;
                    zbuf[zrow * 33 + nt * 16 + rl] = A[mt][nt][r];
                }
        __syncthreads();
        union { f16x4 v; unsigned long long u; } hu;
#pragma unroll
        for (int c2 = 0; c2 < 4; ++c2) {
            int cc = ccB + c2;
            float zi = zbuf[trow * 33 + cc * 4 + 0];
            float zf = zbuf[trow * 33 + cc * 4 + 1];
            float zg = zbuf[trow * 33 + cc * 4 + 2];
            float zo = zbuf[trow * 33 + cc * 4 + 3];
            float iv = sigf(zi + bb[0][c2]);
            float fv = sigf(zf + bb[1][c2]);
            float gv = tanhfast(zg + bb[2][c2]);
            float ov = sigf(zo + bb[3][c2]);
            float cnew = fv * creg[c2] + iv * gv;
            creg[c2] = cnew;
            hu.v[c2] = (_Float16)(ov * tanhfast(cnew));
        }
        __hip_atomic_store(
            (unsigned long long*)(slotW + (size_t)(bat0 + trow) * KA + n0 + ccB),
            hu.u, __ATOMIC_RELAXED, AGENT);
    };

    // phase B: y_t = tanh(h_t @ Wd + bd) -> out, slotT y-section
    auto phaseB = [&](int t, _Float16* slotT) {
        const _Float16* hp = slotT + (size_t)(r0 + rl) * KA + (w << 8) + kg * 8;
        f16x8 ha[8], wa[8];
#pragma unroll
        for (int it = 0; it < 8; ++it)
            ha[it] = *(const f16x8*)(hp + it * 32);
#pragma unroll
        for (int it = 0; it < 8; ++it) {
            int kb = (w << 5) + it * 4 + kg;
            wa[it] = *(const f16x8*)(wdt + ((size_t)rl * 128 + (kb ^ (rl & 7))) * 8);
        }
        f32x4 accB; accB[0] = 0.f; accB[1] = 0.f; accB[2] = 0.f; accB[3] = 0.f;
#pragma unroll
        for (int it = 0; it < 8; ++it)
            accB = __builtin_amdgcn_mfma_f32_16x16x32_f16(ha[it], wa[it], accB, 0, 0, 0);
        float* red = zbuf;
#pragma unroll
        for (int r = 0; r < 4; ++r)
            red[w * 256 + (kg * 4 + r) * 16 + rl] = accB[r];
        __syncthreads();
        int rr = tid >> 4, cc = tid & 15;
        float s = red[rr * 16 + cc] + red[256 + rr * 16 + cc] +
                  red[512 + rr * 16 + cc] + red[768 + rr * 16 + cc];
        float y = tanhfast(s + bdv);
        out[(size_t)(r0 + rr) * 65536 + (size_t)t * 256 + (c0 + cc)] = y;
        union { _Float16 h; unsigned short u; } cv; cv.h = (_Float16)y;
        unsigned short* ys = (unsigned short*)(zbuf + 1024);
        ys[tid] = cv.u;
        __syncthreads();
        if (tid < 64) {
            unsigned long long yv = *(const unsigned long long*)(ys + tid * 4);
            int row = r0 + (tid >> 2), colb = c0 + (tid & 3) * 4;
            __hip_atomic_store(
                (unsigned long long*)(slotT + (size_t)row * KA + 1024 + colb),
                yv, __ATOMIC_RELAXED, AGENT);
        }
    };

    // ---- init barrier: all WfullT reads complete before ring overwrites it ----
    garrive(hflags, bid, 1);
    gwait256(hflags, 1);

    // ---- t = 0: x-only GEMM (h=c=y=0), h_0 -> slot 0 ----
    f32x4 acc[2][2];
#pragma unroll
    for (int mt = 0; mt < 2; ++mt)
#pragma unroll
        for (int nt = 0; nt < 2; ++nt) {
            acc[mt][nt][0] = 0.f; acc[mt][nt][1] = 0.f;
            acc[mt][nt][2] = 0.f; acc[mt][nt][3] = 0.f;
        }
    {
        const _Float16* xb = xh + arow * 65536 + kg * 8;
        auto loadX = [&](int kk, int mt) -> f16x8 {
            return *(const f16x8*)(xb + (size_t)mt * 16 * 65536 + kk * 32);
        };
        gemmPart<8>(loadX, slab, 0, rl, kg, acc);
    }
    epilogue(acc, ring);
    garrive(hflags, bid, 2);

    // ---- pipelined steady loop ----
    for (int t = 0; t < TSTEPS; ++t) {
        // ring-wrap staleness fence (amortized; reuse distance = 16 slots)
        if ((t & 7) == 0)
            __builtin_amdgcn_fence(__ATOMIC_ACQUIRE, "agent");

        _Float16* slotT = ring + (size_t)(t & (RSLOTS - 1)) * SLOTE;

#pragma unroll
        for (int mt = 0; mt < 2; ++mt)
#pragma unroll
            for (int nt = 0; nt < 2; ++nt) {
                acc[mt][nt][0] = 0.f; acc[mt][nt][1] = 0.f;
                acc[mt][nt][2] = 0.f; acc[mt][nt][3] = 0.f;
            }

        if (t < TSTEPS - 1) {   // xGEMM(t+1) — hides h_t flag propagation
            const _Float16* xb = xh + arow * 65536 + (size_t)(t + 1) * 256 + kg * 8;
            auto loadX = [&](int kk, int mt) -> f16x8 {
                return *(const f16x8*)(xb + (size_t)mt * 16 * 65536 + kk * 32);
            };
            gemmPart<8>(loadX, slab, 0, rl, kg, acc);
        }

        gwait(hflags, gbase, t + 2);        // h_t visible group-wide
        phaseB(t, slotT);                   // y_t -> out + ring

        if (t < TSTEPS - 1) {
            garrive(yflags, bid, t + 1);    // y_t announced

            {   // hGEMM(t+1) reading h_t — hides y_t propagation
                const _Float16* hb = slotT + arow * KA + kg * 8;
                auto loadH = [&](int kk, int mt) -> f16x8 {
                    return *(const f16x8*)(hb + (size_t)mt * 16 * KA + kk * 32);
                };
                gemmPart<32>(loadH, slab, 32, rl, kg, acc);
            }

            gwait(yflags, gbase, t + 1);    // y_t visible group-wide

            {   // yGEMM(t+1)
                const _Float16* yb = slotT + arow * KA + 1024 + kg * 8;
                auto loadY = [&](int kk, int mt) -> f16x8 {
                    return *(const f16x8*)(yb + (size_t)mt * 16 * KA + kk * 32);
                };
                gemmPart<8>(loadY, slab, 160, rl, kg, acc);
            }

            epilogue(acc, ring + (size_t)((t + 1) & (RSLOTS - 1)) * SLOTE);
            garrive(hflags, bid, t + 3);    // h_{t+1} announced
        }
    }
}

extern "C" void kernel_launch(void* const* d_in, const int* in_sizes, int n_in,
                              void* d_out, int out_size, void* d_ws, size_t ws_size,
                              hipStream_t stream) {
    const float* x  = (const float*)d_in[0];
    const float* Wx = (const float*)d_in[1];
    const float* Wh = (const float*)d_in[2];
    const float* b  = (const float*)d_in[3];
    const float* Wd = (const float*)d_in[4];
    const float* bd = (const float*)d_in[5];
    float* out = (float*)d_out;
    char* ws = (char*)d_ws;
    if (ws_size < WS_NEEDED) return;

    _Float16* WfullT = (_Float16*)(ws + WFULLT_OFF);
    _Float16* WdT    = (_Float16*)(ws + WDT_OFF);
    _Float16* xh     = (_Float16*)(ws + XH_OFF);
    _Float16* ring   = (_Float16*)(ws + RING_OFF);
    int*      flags  = (int*)(ws + FLAGS_OFF);

    static int lds_set = 0;
    if (!lds_set) {
        hipFuncSetAttribute((const void*)lstm_persist,
                            hipFuncAttributeMaxDynamicSharedMemorySize, LDS_TOTAL);
        lds_set = 1;
    }

    prep_w<<<4352, 256, 0, stream>>>(Wx, Wh, Wd, WfullT, WdT);
    prep_x<<<8192, 256, 0, stream>>>(x, xh, flags);
    lstm_persist<<<NBLK, 256, LDS_TOTAL, stream>>>(WfullT, WdT, xh, b, bd, ring, flags, out);
}

// Round 6
// 4192.246 us; speedup vs baseline: 2.6157x; 1.0160x over previous
//
#include <hip/hip_runtime.h>

// Autoregressive LSTM on MI355X (gfx950).
// B=256, T=256, D=256, H=1024, O=256.
// Persistent 256-block kernel; weights LDS-resident; fence-free steady state
// (sc1 write-through stores + 16-slot ring + acquire fence every 16 steps);
// two independent 128-block groups; software-pipelined step loop.
// Round 6: SYSTEM-scope flags (true L2 bypass -> fast cross-XCD visibility),
// deeper hGEMM prefetch, Wd-reg hoist above wait, NT out stores.

typedef _Float16 f16x8 __attribute__((ext_vector_type(8)));
typedef _Float16 f16x4 __attribute__((ext_vector_type(4)));
typedef float f32x4 __attribute__((ext_vector_type(4)));

#define TSTEPS 256
#define HID 1024
#define OUTD 256
#define KF 1536            // D + H + O (WfullT K)
#define KA 1280            // ring row: h[0..1024) | y[1024..1280)
#define NBLK 256
#define RSLOTS 16
#define SLOTE (256 * KA)   // elements per ring slot

// workspace layout (bytes)
#define RING_OFF   0ull                       // fp16 16*256*1280 = 10,485,760 (aliases WfullT)
#define WFULLT_OFF 0ull                       // fp16 [4096][1536] = 12,582,912 (init-only)
#define WDT_OFF    12582912ull                // fp16 [256][1024]  = 524,288
#define XH_OFF     13107200ull                // fp16 [256][256][256] = 33,554,432
#define FLAGS_OFF  46661632ull                // hflags[256] + yflags[256], 4B packed
#define WS_NEEDED  46663680ull

#define LDS_SLAB_BYTES 98304                  // 32 vcols * 192 kblks * 16B
#define LDS_WDT_BYTES  32768                  // 16 cols * 128 kblks * 16B
#define LDS_ZBUF_BYTES 16896                  // [128][33] f32
#define LDS_TOTAL (LDS_SLAB_BYTES + LDS_WDT_BYTES + LDS_ZBUF_BYTES)

#define AGENT  __HIP_MEMORY_SCOPE_AGENT
#define SYSTEM __HIP_MEMORY_SCOPE_SYSTEM

__device__ __forceinline__ float sigf(float x) {
    return 1.0f / (1.0f + __expf(-x));
}
__device__ __forceinline__ float tanhfast(float x) {
    return 1.0f - 2.0f / (__expf(2.0f * x) + 1.0f);
}

// ---- barrier pieces: packed 4B flags, SYSTEM-scope (L1+L2 bypass) ----
__device__ __forceinline__ void garrive(int* flags, int bid, int ep) {
    __syncthreads();   // drains vmcnt(0): all sc1 data stores at coherence point
    if (threadIdx.x == 0)
        __hip_atomic_store(flags + bid, ep, __ATOMIC_RELAXED, SYSTEM);
}
// group-local wait: 128 flags starting at gbase
__device__ __forceinline__ void gwait(int* flags, int gbase, int ep) {
    if (threadIdx.x < 64) {
        int lane = threadIdx.x;
        for (;;) {
            int a0 = __hip_atomic_load(flags + gbase + lane,      __ATOMIC_RELAXED, SYSTEM);
            int a1 = __hip_atomic_load(flags + gbase + 64 + lane, __ATOMIC_RELAXED, SYSTEM);
            if (min(a0, a1) >= ep) break;
            __builtin_amdgcn_s_sleep(2);
        }
    }
    __syncthreads();
}
// full-grid wait (init only)
__device__ __forceinline__ void gwait256(int* flags, int ep) {
    if (threadIdx.x < 64) {
        int lane = threadIdx.x;
        for (;;) {
            int a0 = __hip_atomic_load(flags + lane,       __ATOMIC_RELAXED, SYSTEM);
            int a1 = __hip_atomic_load(flags + lane + 64,  __ATOMIC_RELAXED, SYSTEM);
            int a2 = __hip_atomic_load(flags + lane + 128, __ATOMIC_RELAXED, SYSTEM);
            int a3 = __hip_atomic_load(flags + lane + 192, __ATOMIC_RELAXED, SYSTEM);
            if (min(min(a0, a1), min(a2, a3)) >= ep) break;
            __builtin_amdgcn_s_sleep(2);
        }
    }
    __syncthreads();
}

// ---------------- prep kernels ----------------
__global__ void prep_w(const float* __restrict__ Wx, const float* __restrict__ Wh,
                       const float* __restrict__ Wd,
                       _Float16* __restrict__ WfullT, _Float16* __restrict__ WdT) {
    int bid = blockIdx.x;
    if (bid < 4096) {
        int n = bid;
        for (int k = threadIdx.x; k < KF; k += 256) {
            float v;
            if (k < 256)       v = Wx[(size_t)k * 4096 + n];
            else if (k < 1280) v = Wh[(size_t)(k - 256) * 4096 + n];
            else               v = Wx[(size_t)(k - 1024) * 4096 + n];
            WfullT[(size_t)n * KF + k] = (_Float16)v;
        }
    } else {
        int o = bid - 4096;
        for (int k = threadIdx.x; k < HID; k += 256) {
            WdT[(size_t)o * HID + k] = (_Float16)Wd[(size_t)k * OUTD + o];
        }
    }
}

__global__ void prep_x(const float* __restrict__ x, _Float16* __restrict__ xh, int* flags) {
    size_t i0 = ((size_t)blockIdx.x * 256 + threadIdx.x) * 8;
    float4 a = *(const float4*)(x + i0);
    float4 c = *(const float4*)(x + i0 + 4);
    f16x8 v;
    v[0] = (_Float16)a.x; v[1] = (_Float16)a.y; v[2] = (_Float16)a.z; v[3] = (_Float16)a.w;
    v[4] = (_Float16)c.x; v[5] = (_Float16)c.y; v[6] = (_Float16)c.z; v[7] = (_Float16)c.w;
    *(f16x8*)(xh + i0) = v;
    if (blockIdx.x == 0) {
        flags[threadIdx.x] = 0;
        flags[256 + threadIdx.x] = 0;
    }
}

// ---------------- GEMM part: NS K-steps of 4 MFMAs, deep A prefetch ----------------
template<int NS, typename AL>
__device__ __forceinline__ void gemmPart(AL&& aload, const _Float16* slab, int kbB,
                                         int rl, int kg, f32x4 (&acc)[2][2]) {
    constexpr int PFD = (NS < 12) ? NS : 12;
    f16x8 pa[PFD][2];
#pragma unroll
    for (int i = 0; i < PFD; ++i) { pa[i][0] = aload(i, 0); pa[i][1] = aload(i, 1); }
    const int sw = rl & 7;
    const _Float16* bb0 = slab + (size_t)rl * 1536;
    const _Float16* bb1 = slab + (size_t)(16 + rl) * 1536;
#pragma unroll
    for (int kk = 0; kk < NS; ++kk) {
        int kblk = kbB + kk * 4 + kg;
        int idx = (kblk ^ sw) * 8;
        f16x8 b0 = *(const f16x8*)(bb0 + idx);
        f16x8 b1 = *(const f16x8*)(bb1 + idx);
        f16x8 a0 = pa[kk % PFD][0];
        f16x8 a1 = pa[kk % PFD][1];
        if (kk + PFD < NS) {
            pa[kk % PFD][0] = aload(kk + PFD, 0);
            pa[kk % PFD][1] = aload(kk + PFD, 1);
        }
        acc[0][0] = __builtin_amdgcn_mfma_f32_16x16x32_f16(a0, b0, acc[0][0], 0, 0, 0);
        acc[0][1] = __builtin_amdgcn_mfma_f32_16x16x32_f16(a0, b1, acc[0][1], 0, 0, 0);
        acc[1][0] = __builtin_amdgcn_mfma_f32_16x16x32_f16(a1, b0, acc[1][0], 0, 0, 0);
        acc[1][1] = __builtin_amdgcn_mfma_f32_16x16x32_f16(a1, b1, acc[1][1], 0, 0, 0);
    }
}

// ---------------- persistent LSTM ----------------
// Group g = bid>>7 (128 blocks) is self-contained (batch rows g*128..+128 for
// both phases). Barriers group-local. Step-t state in ring slot t&15.
__global__ __launch_bounds__(256, 1) void lstm_persist(
        const _Float16* __restrict__ WfullT, const _Float16* __restrict__ WdT,
        const _Float16* __restrict__ xh, const float* __restrict__ b,
        const float* __restrict__ bd,
        _Float16* __restrict__ ring,
        int* flags, float* __restrict__ out) {
    extern __shared__ char dynsm[];
    _Float16* slab = (_Float16*)dynsm;                              // [32][192][8]
    _Float16* wdt  = (_Float16*)(dynsm + LDS_SLAB_BYTES);           // [16][128][8]
    float* zbuf = (float*)(dynsm + LDS_SLAB_BYTES + LDS_WDT_BYTES); // [128][33]

    const int tid = threadIdx.x, bid = blockIdx.x;
    const int w = tid >> 6, lane = tid & 63;
    const int rl = lane & 15, kg = lane >> 4;

    const int bat0 = (bid >> 7) << 7;
    const int n0 = (bid & 127) << 3;
    const int r0 = (bid >> 4) << 4;
    const int c0 = (bid & 15) << 4;
    const int gbase = bid & 128;          // group flag base

    int* hflags = flags;
    int* yflags = flags + 256;

    // ---- init: weight slab + WdT tile (swizzled) into LDS ----
    for (int i = tid; i < 32 * 192; i += 256) {
        int vcol = i / 192, kblk = i % 192;
        int n = (vcol & 3) * 1024 + n0 + (vcol >> 2);
        f16x8 v = *(const f16x8*)(WfullT + (size_t)n * KF + kblk * 8);
        *(f16x8*)(slab + ((size_t)vcol * 192 + (kblk ^ (vcol & 7))) * 8) = v;
    }
    for (int i = tid; i < 16 * 128; i += 256) {
        int wcol = i >> 7, kb = i & 127;
        f16x8 v = *(const f16x8*)(WdT + (size_t)(c0 + wcol) * HID + kb * 8);
        *(f16x8*)(wdt + ((size_t)wcol * 128 + (kb ^ (wcol & 7))) * 8) = v;
    }
    const int trow = tid >> 1;          // 0..127 (epilogue row)
    const int ccB = (tid & 1) * 4;      // epilogue col base (0 or 4)
    float bb[4][4];
#pragma unroll
    for (int g = 0; g < 4; ++g)
#pragma unroll
        for (int c2 = 0; c2 < 4; ++c2)
            bb[g][c2] = b[g * 1024 + n0 + ccB + c2];
    const float bdv = bd[c0 + (tid & 15)];
    float creg[4] = {0.f, 0.f, 0.f, 0.f};

    const size_t arow = (size_t)(bat0 + w * 32 + rl);

    // epilogue: acc(z) -> gates -> c,h; h -> slotW (sc1 write-through)
    auto epilogue = [&](f32x4 (&A)[2][2], _Float16* slotW) {
#pragma unroll
        for (int mt = 0; mt < 2; ++mt)
#pragma unroll
            for (int nt = 0; nt < 2; ++nt)
#pragma unroll
                for (int r = 0; r < 4; ++r) {
                    int zrow = w * 32 + mt * 16 + kg * 4 + r;
                    zbuf[zrow * 33 + nt * 16 + rl] = A[mt][nt][r];
                }
        __syncthreads();
        union { f16x4 v; unsigned long long u; } hu;
#pragma unroll
        for (int c2 = 0; c2 < 4; ++c2) {
            int cc = ccB + c2;
            float zi = zbuf[trow * 33 + cc * 4 + 0];
            float zf = zbuf[trow * 33 + cc * 4 + 1];
            float zg = zbuf[trow * 33 + cc * 4 + 2];
            float zo = zbuf[trow * 33 + cc * 4 + 3];
            float iv = sigf(zi + bb[0][c2]);
            float fv = sigf(zf + bb[1][c2]);
            float gv = tanhfast(zg + bb[2][c2]);
            float ov = sigf(zo + bb[3][c2]);
            float cnew = fv * creg[c2] + iv * gv;
            creg[c2] = cnew;
            hu.v[c2] = (_Float16)(ov * tanhfast(cnew));
        }
        __hip_atomic_store(
            (unsigned long long*)(slotW + (size_t)(bat0 + trow) * KA + n0 + ccB),
            hu.u, __ATOMIC_RELAXED, AGENT);
    };

    // phase B main: y_t = tanh(h_t @ Wd + bd) -> out (NT), slotT y-section
    // (wa preloaded from LDS before the h-wait)
    auto phaseB = [&](int t, _Float16* slotT, const f16x8* wa) {
        const _Float16* hp = slotT + (size_t)(r0 + rl) * KA + (w << 8) + kg * 8;
        f16x8 ha[8];
#pragma unroll
        for (int it = 0; it < 8; ++it)
            ha[it] = *(const f16x8*)(hp + it * 32);
        f32x4 accB; accB[0] = 0.f; accB[1] = 0.f; accB[2] = 0.f; accB[3] = 0.f;
#pragma unroll
        for (int it = 0; it < 8; ++it)
            accB = __builtin_amdgcn_mfma_f32_16x16x32_f16(ha[it], wa[it], accB, 0, 0, 0);
        float* red = zbuf;
#pragma unroll
        for (int r = 0; r < 4; ++r)
            red[w * 256 + (kg * 4 + r) * 16 + rl] = accB[r];
        __syncthreads();
        int rr = tid >> 4, cc = tid & 15;
        float s = red[rr * 16 + cc] + red[256 + rr * 16 + cc] +
                  red[512 + rr * 16 + cc] + red[768 + rr * 16 + cc];
        float y = tanhfast(s + bdv);
        __builtin_nontemporal_store(
            y, out + (size_t)(r0 + rr) * 65536 + (size_t)t * 256 + (c0 + cc));
        union { _Float16 h; unsigned short u; } cv; cv.h = (_Float16)y;
        unsigned short* ys = (unsigned short*)(zbuf + 1024);
        ys[tid] = cv.u;
        __syncthreads();
        if (tid < 64) {
            unsigned long long yv = *(const unsigned long long*)(ys + tid * 4);
            int row = r0 + (tid >> 2), colb = c0 + (tid & 3) * 4;
            __hip_atomic_store(
                (unsigned long long*)(slotT + (size_t)row * KA + 1024 + colb),
                yv, __ATOMIC_RELAXED, AGENT);
        }
    };

    // ---- init barrier: all WfullT reads complete before ring overwrites it ----
    garrive(hflags, bid, 1);
    gwait256(hflags, 1);

    // ---- t = 0: x-only GEMM (h=c=y=0), h_0 -> slot 0 ----
    f32x4 acc[2][2];
#pragma unroll
    for (int mt = 0; mt < 2; ++mt)
#pragma unroll
        for (int nt = 0; nt < 2; ++nt) {
            acc[mt][nt][0] = 0.f; acc[mt][nt][1] = 0.f;
            acc[mt][nt][2] = 0.f; acc[mt][nt][3] = 0.f;
        }
    {
        const _Float16* xb = xh + arow * 65536 + kg * 8;
        auto loadX = [&](int kk, int mt) -> f16x8 {
            return *(const f16x8*)(xb + (size_t)mt * 16 * 65536 + kk * 32);
        };
        gemmPart<8>(loadX, slab, 0, rl, kg, acc);
    }
    epilogue(acc, ring);
    garrive(hflags, bid, 2);

    // ---- pipelined steady loop ----
    for (int t = 0; t < TSTEPS; ++t) {
        // ring-wrap staleness fence (reuse distance = 16 slots; one fence
        // per 16-step window guarantees no stale L1/L2 lines)
        if ((t & 15) == 0)
            __builtin_amdgcn_fence(__ATOMIC_ACQUIRE, "agent");

        _Float16* slotT = ring + (size_t)(t & (RSLOTS - 1)) * SLOTE;

#pragma unroll
        for (int mt = 0; mt < 2; ++mt)
#pragma unroll
            for (int nt = 0; nt < 2; ++nt) {
                acc[mt][nt][0] = 0.f; acc[mt][nt][1] = 0.f;
                acc[mt][nt][2] = 0.f; acc[mt][nt][3] = 0.f;
            }

        if (t < TSTEPS - 1) {   // xGEMM(t+1) — hides h_t flag propagation
            const _Float16* xb = xh + arow * 65536 + (size_t)(t + 1) * 256 + kg * 8;
            auto loadX = [&](int kk, int mt) -> f16x8 {
                return *(const f16x8*)(xb + (size_t)mt * 16 * 65536 + kk * 32);
            };
            gemmPart<8>(loadX, slab, 0, rl, kg, acc);
        }

        // preload phase-B Wd fragments from LDS (independent of the wait)
        f16x8 wa[8];
#pragma unroll
        for (int it = 0; it < 8; ++it) {
            int kb = (w << 5) + it * 4 + kg;
            wa[it] = *(const f16x8*)(wdt + ((size_t)rl * 128 + (kb ^ (rl & 7))) * 8);
        }

        gwait(hflags, gbase, t + 2);        // h_t visible group-wide
        phaseB(t, slotT, wa);               // y_t -> out + ring

        if (t < TSTEPS - 1) {
            garrive(yflags, bid, t + 1);    // y_t announced

            {   // hGEMM(t+1) reading h_t — hides y_t propagation
                const _Float16* hb = slotT + arow * KA + kg * 8;
                auto loadH = [&](int kk, int mt) -> f16x8 {
                    return *(const f16x8*)(hb + (size_t)mt * 16 * KA + kk * 32);
                };
                gemmPart<32>(loadH, slab, 32, rl, kg, acc);
            }

            gwait(yflags, gbase, t + 1);    // y_t visible group-wide

            {   // yGEMM(t+1)
                const _Float16* yb = slotT + arow * KA + 1024 + kg * 8;
                auto loadY = [&](int kk, int mt) -> f16x8 {
                    return *(const f16x8*)(yb + (size_t)mt * 16 * KA + kk * 32);
                };
                gemmPart<8>(loadY, slab, 160, rl, kg, acc);
            }

            epilogue(acc, ring + (size_t)((t + 1) & (RSLOTS - 1)) * SLOTE);
            garrive(hflags, bid, t + 3);    // h_{t+1} announced
        }
    }
}

extern "C" void kernel_launch(void* const* d_in, const int* in_sizes, int n_in,
                              void* d_out, int out_size, void* d_ws, size_t ws_size,
                              hipStream_t stream) {
    const float* x  = (const float*)d_in[0];
    const float* Wx = (const float*)d_in[1];
    const float* Wh = (const float*)d_in[2];
    const float* b  = (const float*)d_in[3];
    const float* Wd = (const float*)d_in[4];
    const float* bd = (const float*)d_in[5];
    float* out = (float*)d_out;
    char* ws = (char*)d_ws;
    if (ws_size < WS_NEEDED) return;

    _Float16* WfullT = (_Float16*)(ws + WFULLT_OFF);
    _Float16* WdT    = (_Float16*)(ws + WDT_OFF);
    _Float16* xh     = (_Float16*)(ws + XH_OFF);
    _Float16* ring   = (_Float16*)(ws + RING_OFF);
    int*      flags  = (int*)(ws + FLAGS_OFF);

    static int lds_set = 0;
    if (!lds_set) {
        hipFuncSetAttribute((const void*)lstm_persist,
                            hipFuncAttributeMaxDynamicSharedMemorySize, LDS_TOTAL);
        lds_set = 1;
    }

    prep_w<<<4352, 256, 0, stream>>>(Wx, Wh, Wd, WfullT, WdT);
    prep_x<<<8192, 256, 0, stream>>>(x, xh, flags);
    lstm_persist<<<NBLK, 256, LDS_TOTAL, stream>>>(WfullT, WdT, xh, b, bd, ring, flags, out);
}

// Round 7
// 4176.395 us; speedup vs baseline: 2.6256x; 1.0038x over previous
//
#include <hip/hip_runtime.h>

// Autoregressive LSTM on MI355X (gfx950).
// B=256, T=256, D=256, H=1024, O=256.
// Persistent 256-block kernel; weights LDS-resident; fence-free steady state
// (sc1 write-through stores + 16-slot ring + acquire fence every 16 steps);
// two independent 128-block groups; software-pipelined step loop.
// Round 7: sub-counter barrier — arrivals via relaxed atomic_add into 8
// packed sub-counters (one 64B line per group/type), waiters poll ONE line.
// Kills the 8-line-per-poll-per-block MALL storm of the flag-array barrier.

typedef _Float16 f16x8 __attribute__((ext_vector_type(8)));
typedef _Float16 f16x4 __attribute__((ext_vector_type(4)));
typedef float f32x4 __attribute__((ext_vector_type(4)));

#define TSTEPS 256
#define HID 1024
#define OUTD 256
#define KF 1536            // D + H + O (WfullT K)
#define KA 1280            // ring row: h[0..1024) | y[1024..1280)
#define NBLK 256
#define RSLOTS 16
#define SLOTE (256 * KA)   // elements per ring slot

// workspace layout (bytes)
#define RING_OFF   0ull                       // fp16 16*256*1280 = 10,485,760 (aliases WfullT)
#define WFULLT_OFF 0ull                       // fp16 [4096][1536] = 12,582,912 (init-only)
#define WDT_OFF    12582912ull                // fp16 [256][1024]  = 524,288
#define XH_OFF     13107200ull                // fp16 [256][256][256] = 33,554,432
#define CNT_OFF    46661632ull                // sub-counters (1KB region)
#define WS_NEEDED  46663680ull

// counter layout (ints): hcnt grp0 @0..8, grp1 @64..72; ycnt grp0 @128..136, grp1 @192..200
#define HCNT(g) ((g) * 64)
#define YCNT(g) (128 + (g) * 64)

#define LDS_SLAB_BYTES 98304                  // 32 vcols * 192 kblks * 16B
#define LDS_WDT_BYTES  32768                  // 16 cols * 128 kblks * 16B
#define LDS_ZBUF_BYTES 16896                  // [128][33] f32
#define LDS_TOTAL (LDS_SLAB_BYTES + LDS_WDT_BYTES + LDS_ZBUF_BYTES)

#define AGENT  __HIP_MEMORY_SCOPE_AGENT

__device__ __forceinline__ float sigf(float x) {
    return 1.0f / (1.0f + __expf(-x));
}
__device__ __forceinline__ float tanhfast(float x) {
    return 1.0f - 2.0f / (__expf(2.0f * x) + 1.0f);
}

// ---- sub-counter barrier ----
// arrive: __syncthreads (vmcnt(0): all sc1 data stores retired at MALL), then
// one relaxed agent-scope atomic add into sub-counter j (16 blocks share j).
// wait: lanes 0..7 spin on their own word; all 8 words in ONE 64B line ->
// one coalesced MALL request per poll per block.
__device__ __forceinline__ void garrive(int* base, int j) {
    __syncthreads();
    if (threadIdx.x == 0)
        __hip_atomic_fetch_add(base + j, 1, __ATOMIC_RELAXED, AGENT);
}
__device__ __forceinline__ void gwait(int* base, int target) {
    if (threadIdx.x < 8) {
        while (__hip_atomic_load(base + threadIdx.x, __ATOMIC_RELAXED, AGENT) < target)
            __builtin_amdgcn_s_sleep(2);
    }
    __syncthreads();
}
// init-only: wait on both groups' h-counters
__device__ __forceinline__ void gwait_both(int* cnts, int target) {
    if (threadIdx.x < 8) {
        while (__hip_atomic_load(cnts + HCNT(0) + threadIdx.x, __ATOMIC_RELAXED, AGENT) < target ||
               __hip_atomic_load(cnts + HCNT(1) + threadIdx.x, __ATOMIC_RELAXED, AGENT) < target)
            __builtin_amdgcn_s_sleep(2);
    }
    __syncthreads();
}

// ---------------- prep kernels ----------------
__global__ void prep_w(const float* __restrict__ Wx, const float* __restrict__ Wh,
                       const float* __restrict__ Wd,
                       _Float16* __restrict__ WfullT, _Float16* __restrict__ WdT) {
    int bid = blockIdx.x;
    if (bid < 4096) {
        int n = bid;
        for (int k = threadIdx.x; k < KF; k += 256) {
            float v;
            if (k < 256)       v = Wx[(size_t)k * 4096 + n];
            else if (k < 1280) v = Wh[(size_t)(k - 256) * 4096 + n];
            else               v = Wx[(size_t)(k - 1024) * 4096 + n];
            WfullT[(size_t)n * KF + k] = (_Float16)v;
        }
    } else {
        int o = bid - 4096;
        for (int k = threadIdx.x; k < HID; k += 256) {
            WdT[(size_t)o * HID + k] = (_Float16)Wd[(size_t)k * OUTD + o];
        }
    }
}

__global__ void prep_x(const float* __restrict__ x, _Float16* __restrict__ xh, int* cnts) {
    size_t i0 = ((size_t)blockIdx.x * 256 + threadIdx.x) * 8;
    float4 a = *(const float4*)(x + i0);
    float4 c = *(const float4*)(x + i0 + 4);
    f16x8 v;
    v[0] = (_Float16)a.x; v[1] = (_Float16)a.y; v[2] = (_Float16)a.z; v[3] = (_Float16)a.w;
    v[4] = (_Float16)c.x; v[5] = (_Float16)c.y; v[6] = (_Float16)c.z; v[7] = (_Float16)c.w;
    *(f16x8*)(xh + i0) = v;
    if (blockIdx.x == 0) cnts[threadIdx.x] = 0;   // zero 1KB counter region
}

// ---------------- GEMM part: NS K-steps of 4 MFMAs, deep A prefetch ----------------
template<int NS, typename AL>
__device__ __forceinline__ void gemmPart(AL&& aload, const _Float16* slab, int kbB,
                                         int rl, int kg, f32x4 (&acc)[2][2]) {
    constexpr int PFD = (NS < 12) ? NS : 12;
    f16x8 pa[PFD][2];
#pragma unroll
    for (int i = 0; i < PFD; ++i) { pa[i][0] = aload(i, 0); pa[i][1] = aload(i, 1); }
    const int sw = rl & 7;
    const _Float16* bb0 = slab + (size_t)rl * 1536;
    const _Float16* bb1 = slab + (size_t)(16 + rl) * 1536;
#pragma unroll
    for (int kk = 0; kk < NS; ++kk) {
        int kblk = kbB + kk * 4 + kg;
        int idx = (kblk ^ sw) * 8;
        f16x8 b0 = *(const f16x8*)(bb0 + idx);
        f16x8 b1 = *(const f16x8*)(bb1 + idx);
        f16x8 a0 = pa[kk % PFD][0];
        f16x8 a1 = pa[kk % PFD][1];
        if (kk + PFD < NS) {
            pa[kk % PFD][0] = aload(kk + PFD, 0);
            pa[kk % PFD][1] = aload(kk + PFD, 1);
        }
        acc[0][0] = __builtin_amdgcn_mfma_f32_16x16x32_f16(a0, b0, acc[0][0], 0, 0, 0);
        acc[0][1] = __builtin_amdgcn_mfma_f32_16x16x32_f16(a0, b1, acc[0][1], 0, 0, 0);
        acc[1][0] = __builtin_amdgcn_mfma_f32_16x16x32_f16(a1, b0, acc[1][0], 0, 0, 0);
        acc[1][1] = __builtin_amdgcn_mfma_f32_16x16x32_f16(a1, b1, acc[1][1], 0, 0, 0);
    }
}

// ---------------- persistent LSTM ----------------
// Group g = bid>>7 (128 blocks) is self-contained (batch rows g*128..+128 for
// both phases). Barriers group-local via sub-counters. Step-t state in ring
// slot t&15.
__global__ __launch_bounds__(256, 1) void lstm_persist(
        const _Float16* __restrict__ WfullT, const _Float16* __restrict__ WdT,
        const _Float16* __restrict__ xh, const float* __restrict__ b,
        const float* __restrict__ bd,
        _Float16* __restrict__ ring,
        int* cnts, float* __restrict__ out) {
    extern __shared__ char dynsm[];
    _Float16* slab = (_Float16*)dynsm;                              // [32][192][8]
    _Float16* wdt  = (_Float16*)(dynsm + LDS_SLAB_BYTES);           // [16][128][8]
    float* zbuf = (float*)(dynsm + LDS_SLAB_BYTES + LDS_WDT_BYTES); // [128][33]

    const int tid = threadIdx.x, bid = blockIdx.x;
    const int w = tid >> 6, lane = tid & 63;
    const int rl = lane & 15, kg = lane >> 4;

    const int bat0 = (bid >> 7) << 7;
    const int n0 = (bid & 127) << 3;
    const int r0 = (bid >> 4) << 4;
    const int c0 = (bid & 15) << 4;
    const int gid = bid >> 7;
    const int subj = (bid >> 4) & 7;      // 16 blocks per sub-counter

    int* hcnt = cnts + HCNT(gid);
    int* ycnt = cnts + YCNT(gid);

    // ---- init: weight slab + WdT tile (swizzled) into LDS ----
    for (int i = tid; i < 32 * 192; i += 256) {
        int vcol = i / 192, kblk = i % 192;
        int n = (vcol & 3) * 1024 + n0 + (vcol >> 2);
        f16x8 v = *(const f16x8*)(WfullT + (size_t)n * KF + kblk * 8);
        *(f16x8*)(slab + ((size_t)vcol * 192 + (kblk ^ (vcol & 7))) * 8) = v;
    }
    for (int i = tid; i < 16 * 128; i += 256) {
        int wcol = i >> 7, kb = i & 127;
        f16x8 v = *(const f16x8*)(WdT + (size_t)(c0 + wcol) * HID + kb * 8);
        *(f16x8*)(wdt + ((size_t)wcol * 128 + (kb ^ (wcol & 7))) * 8) = v;
    }
    const int trow = tid >> 1;          // 0..127 (epilogue row)
    const int ccB = (tid & 1) * 4;      // epilogue col base (0 or 4)
    float bb[4][4];
#pragma unroll
    for (int g = 0; g < 4; ++g)
#pragma unroll
        for (int c2 = 0; c2 < 4; ++c2)
            bb[g][c2] = b[g * 1024 + n0 + ccB + c2];
    const float bdv = bd[c0 + (tid & 15)];
    float creg[4] = {0.f, 0.f, 0.f, 0.f};

    const size_t arow = (size_t)(bat0 + w * 32 + rl);

    // epilogue: acc(z) -> gates -> c,h; h -> slotW (sc1 write-through)
    auto epilogue = [&](f32x4 (&A)[2][2], _Float16* slotW) {
#pragma unroll
        for (int mt = 0; mt < 2; ++mt)
#pragma unroll
            for (int nt = 0; nt < 2; ++nt)
#pragma unroll
                for (int r = 0; r < 4; ++r) {
                    int zrow = w * 32 + mt * 16 + kg * 4 + r;
                    zbuf[zrow * 33 + nt * 16 + rl] = A[mt][nt][r];
                }
        __syncthreads();
        union { f16x4 v; unsigned long long u; } hu;
#pragma unroll
        for (int c2 = 0; c2 < 4; ++c2) {
            int cc = ccB + c2;
            float zi = zbuf[trow * 33 + cc * 4 + 0];
            float zf = zbuf[trow * 33 + cc * 4 + 1];
            float zg = zbuf[trow * 33 + cc * 4 + 2];
            float zo = zbuf[trow * 33 + cc * 4 + 3];
            float iv = sigf(zi + bb[0][c2]);
            float fv = sigf(zf + bb[1][c2]);
            float gv = tanhfast(zg + bb[2][c2]);
            float ov = sigf(zo + bb[3][c2]);
            float cnew = fv * creg[c2] + iv * gv;
            creg[c2] = cnew;
            hu.v[c2] = (_Float16)(ov * tanhfast(cnew));
        }
        __hip_atomic_store(
            (unsigned long long*)(slotW + (size_t)(bat0 + trow) * KA + n0 + ccB),
            hu.u, __ATOMIC_RELAXED, AGENT);
    };

    // phase B main: y_t = tanh(h_t @ Wd + bd) -> out (NT), slotT y-section
    auto phaseB = [&](int t, _Float16* slotT, const f16x8* wa) {
        const _Float16* hp = slotT + (size_t)(r0 + rl) * KA + (w << 8) + kg * 8;
        f16x8 ha[8];
#pragma unroll
        for (int it = 0; it < 8; ++it)
            ha[it] = *(const f16x8*)(hp + it * 32);
        f32x4 accB; accB[0] = 0.f; accB[1] = 0.f; accB[2] = 0.f; accB[3] = 0.f;
#pragma unroll
        for (int it = 0; it < 8; ++it)
            accB = __builtin_amdgcn_mfma_f32_16x16x32_f16(ha[it], wa[it], accB, 0, 0, 0);
        float* red = zbuf;
#pragma unroll
        for (int r = 0; r < 4; ++r)
            red[w * 256 + (kg * 4 + r) * 16 + rl] = accB[r];
        __syncthreads();
        int rr = tid >> 4, cc = tid & 15;
        float s = red[rr * 16 + cc] + red[256 + rr * 16 + cc] +
                  red[512 + rr * 16 + cc] + red[768 + rr * 16 + cc];
        float y = tanhfast(s + bdv);
        __builtin_nontemporal_store(
            y, out + (size_t)(r0 + rr) * 65536 + (size_t)t * 256 + (c0 + cc));
        union { _Float16 h; unsigned short u; } cv; cv.h = (_Float16)y;
        unsigned short* ys = (unsigned short*)(zbuf + 1024);
        ys[tid] = cv.u;
        __syncthreads();
        if (tid < 64) {
            unsigned long long yv = *(const unsigned long long*)(ys + tid * 4);
            int row = r0 + (tid >> 2), colb = c0 + (tid & 3) * 4;
            __hip_atomic_store(
                (unsigned long long*)(slotT + (size_t)row * KA + 1024 + colb),
                yv, __ATOMIC_RELAXED, AGENT);
        }
    };

    // ---- init barrier: all WfullT reads complete before ring overwrites it ----
    garrive(hcnt, subj);            // epoch 1 (target 16 per sub-counter)
    gwait_both(cnts, 16);

    // ---- t = 0: x-only GEMM (h=c=y=0), h_0 -> slot 0 ----
    f32x4 acc[2][2];
#pragma unroll
    for (int mt = 0; mt < 2; ++mt)
#pragma unroll
        for (int nt = 0; nt < 2; ++nt) {
            acc[mt][nt][0] = 0.f; acc[mt][nt][1] = 0.f;
            acc[mt][nt][2] = 0.f; acc[mt][nt][3] = 0.f;
        }
    {
        const _Float16* xb = xh + arow * 65536 + kg * 8;
        auto loadX = [&](int kk, int mt) -> f16x8 {
            return *(const f16x8*)(xb + (size_t)mt * 16 * 65536 + kk * 32);
        };
        gemmPart<8>(loadX, slab, 0, rl, kg, acc);
    }
    epilogue(acc, ring);
    garrive(hcnt, subj);            // h_0 announced (epoch 2)

    // ---- pipelined steady loop ----
    for (int t = 0; t < TSTEPS; ++t) {
        // ring-wrap staleness fence (reuse distance = 16 slots)
        if ((t & 15) == 0)
            __builtin_amdgcn_fence(__ATOMIC_ACQUIRE, "agent");

        _Float16* slotT = ring + (size_t)(t & (RSLOTS - 1)) * SLOTE;

#pragma unroll
        for (int mt = 0; mt < 2; ++mt)
#pragma unroll
            for (int nt = 0; nt < 2; ++nt) {
                acc[mt][nt][0] = 0.f; acc[mt][nt][1] = 0.f;
                acc[mt][nt][2] = 0.f; acc[mt][nt][3] = 0.f;
            }

        if (t < TSTEPS - 1) {   // xGEMM(t+1) — hides h_t flag propagation
            const _Float16* xb = xh + arow * 65536 + (size_t)(t + 1) * 256 + kg * 8;
            auto loadX = [&](int kk, int mt) -> f16x8 {
                return *(const f16x8*)(xb + (size_t)mt * 16 * 65536 + kk * 32);
            };
            gemmPart<8>(loadX, slab, 0, rl, kg, acc);
        }

        // preload phase-B Wd fragments from LDS (independent of the wait)
        f16x8 wa[8];
#pragma unroll
        for (int it = 0; it < 8; ++it) {
            int kb = (w << 5) + it * 4 + kg;
            wa[it] = *(const f16x8*)(wdt + ((size_t)rl * 128 + (kb ^ (rl & 7))) * 8);
        }

        gwait(hcnt, (t + 2) * 16);          // h_t visible group-wide
        phaseB(t, slotT, wa);               // y_t -> out + ring

        if (t < TSTEPS - 1) {
            garrive(ycnt, subj);            // y_t announced (epoch t+1)

            {   // hGEMM(t+1) reading h_t — hides y_t propagation
                const _Float16* hb = slotT + arow * KA + kg * 8;
                auto loadH = [&](int kk, int mt) -> f16x8 {
                    return *(const f16x8*)(hb + (size_t)mt * 16 * KA + kk * 32);
                };
                gemmPart<32>(loadH, slab, 32, rl, kg, acc);
            }

            gwait(ycnt, (t + 1) * 16);      // y_t visible group-wide

            {   // yGEMM(t+1)
                const _Float16* yb = slotT + arow * KA + 1024 + kg * 8;
                auto loadY = [&](int kk, int mt) -> f16x8 {
                    return *(const f16x8*)(yb + (size_t)mt * 16 * KA + kk * 32);
                };
                gemmPart<8>(loadY, slab, 160, rl, kg, acc);
            }

            epilogue(acc, ring + (size_t)((t + 1) & (RSLOTS - 1)) * SLOTE);
            garrive(hcnt, subj);            // h_{t+1} announced (epoch t+3)
        }
    }
}

extern "C" void kernel_launch(void* const* d_in, const int* in_sizes, int n_in,
                              void* d_out, int out_size, void* d_ws, size_t ws_size,
                              hipStream_t stream) {
    const float* x  = (const float*)d_in[0];
    const float* Wx = (const float*)d_in[1];
    const float* Wh = (const float*)d_in[2];
    const float* b  = (const float*)d_in[3];
    const float* Wd = (const float*)d_in[4];
    const float* bd = (const float*)d_in[5];
    float* out = (float*)d_out;
    char* ws = (char*)d_ws;
    if (ws_size < WS_NEEDED) return;

    _Float16* WfullT = (_Float16*)(ws + WFULLT_OFF);
    _Float16* WdT    = (_Float16*)(ws + WDT_OFF);
    _Float16* xh     = (_Float16*)(ws + XH_OFF);
    _Float16* ring   = (_Float16*)(ws + RING_OFF);
    int*      cnts   = (int*)(ws + CNT_OFF);

    static int lds_set = 0;
    if (!lds_set) {
        hipFuncSetAttribute((const void*)lstm_persist,
                            hipFuncAttributeMaxDynamicSharedMemorySize, LDS_TOTAL);
        lds_set = 1;
    }

    prep_w<<<4352, 256, 0, stream>>>(Wx, Wh, Wd, WfullT, WdT);
    prep_x<<<8192, 256, 0, stream>>>(x, xh, cnts);
    lstm_persist<<<NBLK, 256, LDS_TOTAL, stream>>>(WfullT, WdT, xh, b, bd, ring, cnts, out);
}

// Round 9
// 3929.688 us; speedup vs baseline: 2.7905x; 1.0628x over previous
//
#include <hip/hip_runtime.h>

// Autoregressive LSTM on MI355X (gfx950).
// B=256, T=256, D=256, H=1024, O=256.
// Persistent 256-block kernel; weights LDS-resident; fence-free steady state
// (sc1 write-through stores + 16-slot ring + acquire fence every 16 steps);
// two independent 128-block groups; software-pipelined step loop.
// Round 9 (hybrid bisect): 512 threads. Phase A uses all 8 waves (16 rows
// each, 2 waves/SIMD TLP). Epilogue + phase B are byte-level Round-7 code
// running on the first 256 threads / 4 waves (R7 passed correctness).

typedef _Float16 f16x8 __attribute__((ext_vector_type(8)));
typedef _Float16 f16x4 __attribute__((ext_vector_type(4)));
typedef float f32x4 __attribute__((ext_vector_type(4)));

#define TSTEPS 256
#define HID 1024
#define OUTD 256
#define KF 1536            // D + H + O (WfullT K)
#define KA 1280            // ring row: h[0..1024) | y[1024..1280)
#define NBLK 256
#define RSLOTS 16
#define SLOTE (256 * KA)   // elements per ring slot

// workspace layout (bytes)
#define RING_OFF   0ull                       // fp16 16*256*1280 = 10,485,760 (aliases WfullT)
#define WFULLT_OFF 0ull                       // fp16 [4096][1536] = 12,582,912 (init-only)
#define WDT_OFF    12582912ull                // fp16 [256][1024]  = 524,288
#define XH_OFF     13107200ull                // fp16 [256][256][256] = 33,554,432
#define CNT_OFF    46661632ull                // sub-counters (1KB region)
#define WS_NEEDED  46663680ull

// counter layout (ints): hcnt grp0 @0..8, grp1 @64..72; ycnt grp0 @128..136, grp1 @192..200
#define HCNT(g) ((g) * 64)
#define YCNT(g) (128 + (g) * 64)

#define LDS_SLAB_BYTES 98304                  // 32 vcols * 192 kblks * 16B
#define LDS_WDT_BYTES  32768                  // 16 cols * 128 kblks * 16B
#define LDS_ZBUF_BYTES 16896                  // [128][33] f32
#define LDS_TOTAL (LDS_SLAB_BYTES + LDS_WDT_BYTES + LDS_ZBUF_BYTES)

#define AGENT  __HIP_MEMORY_SCOPE_AGENT

__device__ __forceinline__ float sigf(float x) {
    return 1.0f / (1.0f + __expf(-x));
}
__device__ __forceinline__ float tanhfast(float x) {
    return 1.0f - 2.0f / (__expf(2.0f * x) + 1.0f);
}

// ---- sub-counter barrier (one 64B line per group/type) ----
__device__ __forceinline__ void garrive(int* base, int j) {
    __syncthreads();   // vmcnt(0): all sc1 data stores retired at coherence point
    if (threadIdx.x == 0)
        __hip_atomic_fetch_add(base + j, 1, __ATOMIC_RELAXED, AGENT);
}
__device__ __forceinline__ void gwait(int* base, int target) {
    if (threadIdx.x < 8) {
        while (__hip_atomic_load(base + threadIdx.x, __ATOMIC_RELAXED, AGENT) < target)
            __builtin_amdgcn_s_sleep(2);
    }
    __syncthreads();
}
__device__ __forceinline__ void gwait_both(int* cnts, int target) {
    if (threadIdx.x < 8) {
        while (__hip_atomic_load(cnts + HCNT(0) + threadIdx.x, __ATOMIC_RELAXED, AGENT) < target ||
               __hip_atomic_load(cnts + HCNT(1) + threadIdx.x, __ATOMIC_RELAXED, AGENT) < target)
            __builtin_amdgcn_s_sleep(2);
    }
    __syncthreads();
}

// ---------------- prep kernels ----------------
__global__ void prep_w(const float* __restrict__ Wx, const float* __restrict__ Wh,
                       const float* __restrict__ Wd,
                       _Float16* __restrict__ WfullT, _Float16* __restrict__ WdT) {
    int bid = blockIdx.x;
    if (bid < 4096) {
        int n = bid;
        for (int k = threadIdx.x; k < KF; k += 256) {
            float v;
            if (k < 256)       v = Wx[(size_t)k * 4096 + n];
            else if (k < 1280) v = Wh[(size_t)(k - 256) * 4096 + n];
            else               v = Wx[(size_t)(k - 1024) * 4096 + n];
            WfullT[(size_t)n * KF + k] = (_Float16)v;
        }
    } else {
        int o = bid - 4096;
        for (int k = threadIdx.x; k < HID; k += 256) {
            WdT[(size_t)o * HID + k] = (_Float16)Wd[(size_t)k * OUTD + o];
        }
    }
}

__global__ void prep_x(const float* __restrict__ x, _Float16* __restrict__ xh, int* cnts) {
    size_t i0 = ((size_t)blockIdx.x * 256 + threadIdx.x) * 8;
    float4 a = *(const float4*)(x + i0);
    float4 c = *(const float4*)(x + i0 + 4);
    f16x8 v;
    v[0] = (_Float16)a.x; v[1] = (_Float16)a.y; v[2] = (_Float16)a.z; v[3] = (_Float16)a.w;
    v[4] = (_Float16)c.x; v[5] = (_Float16)c.y; v[6] = (_Float16)c.z; v[7] = (_Float16)c.w;
    *(f16x8*)(xh + i0) = v;
    if (blockIdx.x == 0) cnts[threadIdx.x] = 0;   // zero 1KB counter region
}

// ---------------- GEMM part: NS K-steps of 2 MFMAs, deep A prefetch ----------------
// One M-tile (16 rows) per wave, 2 N-tiles (32 vcols).
template<int NS, typename AL>
__device__ __forceinline__ void gemmPart(AL&& aload, const _Float16* slab, int kbB,
                                         int rl, int kg, f32x4 (&acc)[2]) {
    constexpr int PFD = (NS < 12) ? NS : 12;
    f16x8 pa[PFD];
#pragma unroll
    for (int i = 0; i < PFD; ++i) pa[i] = aload(i);
    const int sw = rl & 7;
    const _Float16* bb0 = slab + (size_t)rl * 1536;
    const _Float16* bb1 = slab + (size_t)(16 + rl) * 1536;
#pragma unroll
    for (int kk = 0; kk < NS; ++kk) {
        int kblk = kbB + kk * 4 + kg;
        int idx = (kblk ^ sw) * 8;
        f16x8 b0 = *(const f16x8*)(bb0 + idx);
        f16x8 b1 = *(const f16x8*)(bb1 + idx);
        f16x8 a0 = pa[kk % PFD];
        if (kk + PFD < NS) pa[kk % PFD] = aload(kk + PFD);
        acc[0] = __builtin_amdgcn_mfma_f32_16x16x32_f16(a0, b0, acc[0], 0, 0, 0);
        acc[1] = __builtin_amdgcn_mfma_f32_16x16x32_f16(a0, b1, acc[1], 0, 0, 0);
    }
}

// ---------------- persistent LSTM ----------------
// 512 threads = 8 waves; phase A: wave w owns batch rows bat0 + w*16 .. +16.
// Epilogue + phase B: Round-7 code on tid<256 (4 waves), w<4 for phase-B MFMA.
__global__ __launch_bounds__(512, 2) void lstm_persist(
        const _Float16* __restrict__ WfullT, const _Float16* __restrict__ WdT,
        const _Float16* __restrict__ xh, const float* __restrict__ b,
        const float* __restrict__ bd,
        _Float16* __restrict__ ring,
        int* cnts, float* __restrict__ out) {
    extern __shared__ char dynsm[];
    _Float16* slab = (_Float16*)dynsm;                              // [32][192][8]
    _Float16* wdt  = (_Float16*)(dynsm + LDS_SLAB_BYTES);           // [16][128][8]
    float* zbuf = (float*)(dynsm + LDS_SLAB_BYTES + LDS_WDT_BYTES); // [128][33]

    const int tid = threadIdx.x, bid = blockIdx.x;
    const int w = tid >> 6, lane = tid & 63;
    const int rl = lane & 15, kg = lane >> 4;

    const int bat0 = (bid >> 7) << 7;
    const int n0 = (bid & 127) << 3;
    const int r0 = (bid >> 4) << 4;
    const int c0 = (bid & 15) << 4;
    const int gid = bid >> 7;
    const int subj = (bid >> 4) & 7;      // 16 blocks per sub-counter

    int* hcnt = cnts + HCNT(gid);
    int* ycnt = cnts + YCNT(gid);

    // ---- init: weight slab + WdT tile (swizzled) into LDS ----
    for (int i = tid; i < 32 * 192; i += 512) {
        int vcol = i / 192, kblk = i % 192;
        int n = (vcol & 3) * 1024 + n0 + (vcol >> 2);
        f16x8 v = *(const f16x8*)(WfullT + (size_t)n * KF + kblk * 8);
        *(f16x8*)(slab + ((size_t)vcol * 192 + (kblk ^ (vcol & 7))) * 8) = v;
    }
    for (int i = tid; i < 16 * 128; i += 512) {
        int wcol = i >> 7, kb = i & 127;
        f16x8 v = *(const f16x8*)(WdT + (size_t)(c0 + wcol) * HID + kb * 8);
        *(f16x8*)(wdt + ((size_t)wcol * 128 + (kb ^ (wcol & 7))) * 8) = v;
    }
    // R7 epilogue mapping (tid<256 active)
    const int trow = tid >> 1;          // 0..127 for tid<256
    const int ccB = (tid & 1) * 4;      // 0 or 4
    float bb[4][4];
#pragma unroll
    for (int g = 0; g < 4; ++g)
#pragma unroll
        for (int c2 = 0; c2 < 4; ++c2)
            bb[g][c2] = b[g * 1024 + n0 + ((ccB + c2) & 7)];
    const float bdv = bd[c0 + (tid & 15)];
    float creg[4] = {0.f, 0.f, 0.f, 0.f};

    const size_t arow = (size_t)(bat0 + w * 16 + rl);

    // epilogue: acc(z) -> zbuf; R7 gate/c/h path on tid<256; h -> slotW (sc1)
    auto epilogue = [&](f32x4 (&A)[2], _Float16* slotW) {
#pragma unroll
        for (int nt = 0; nt < 2; ++nt)
#pragma unroll
            for (int r = 0; r < 4; ++r) {
                int zrow = w * 16 + kg * 4 + r;
                zbuf[zrow * 33 + nt * 16 + rl] = A[nt][r];
            }
        __syncthreads();
        if (tid < 256) {
            union { f16x4 v; unsigned long long u; } hu;
#pragma unroll
            for (int c2 = 0; c2 < 4; ++c2) {
                int cc = ccB + c2;
                float zi = zbuf[trow * 33 + cc * 4 + 0];
                float zf = zbuf[trow * 33 + cc * 4 + 1];
                float zg = zbuf[trow * 33 + cc * 4 + 2];
                float zo = zbuf[trow * 33 + cc * 4 + 3];
                float iv = sigf(zi + bb[0][c2]);
                float fv = sigf(zf + bb[1][c2]);
                float gv = tanhfast(zg + bb[2][c2]);
                float ov = sigf(zo + bb[3][c2]);
                float cnew = fv * creg[c2] + iv * gv;
                creg[c2] = cnew;
                hu.v[c2] = (_Float16)(ov * tanhfast(cnew));
            }
            __hip_atomic_store(
                (unsigned long long*)(slotW + (size_t)(bat0 + trow) * KA + n0 + ccB),
                hu.u, __ATOMIC_RELAXED, AGENT);
        }
    };

    // phase B (R7): waves 0-3 compute, K slice 256/wave; y -> out (NT) + slotT
    auto phaseB = [&](int t, _Float16* slotT, const f16x8* wa) {
        float* red = zbuf;
        if (w < 4) {
            const _Float16* hp = slotT + (size_t)(r0 + rl) * KA + (w << 8) + kg * 8;
            f16x8 ha[8];
#pragma unroll
            for (int it = 0; it < 8; ++it)
                ha[it] = *(const f16x8*)(hp + it * 32);
            f32x4 accB; accB[0] = 0.f; accB[1] = 0.f; accB[2] = 0.f; accB[3] = 0.f;
#pragma unroll
            for (int it = 0; it < 8; ++it)
                accB = __builtin_amdgcn_mfma_f32_16x16x32_f16(ha[it], wa[it], accB, 0, 0, 0);
#pragma unroll
            for (int r = 0; r < 4; ++r)
                red[w * 256 + (kg * 4 + r) * 16 + rl] = accB[r];
        }
        __syncthreads();
        unsigned short* ys = (unsigned short*)(zbuf + 1024);
        if (tid < 256) {
            int rr = tid >> 4, cc = tid & 15;
            float s = red[rr * 16 + cc] + red[256 + rr * 16 + cc] +
                      red[512 + rr * 16 + cc] + red[768 + rr * 16 + cc];
            float y = tanhfast(s + bdv);
            __builtin_nontemporal_store(
                y, out + (size_t)(r0 + rr) * 65536 + (size_t)t * 256 + (c0 + cc));
            union { _Float16 h; unsigned short u; } cv; cv.h = (_Float16)y;
            ys[tid] = cv.u;
        }
        __syncthreads();
        if (tid < 64) {
            unsigned long long yv = *(const unsigned long long*)(ys + tid * 4);
            int row = r0 + (tid >> 2), colb = c0 + (tid & 3) * 4;
            __hip_atomic_store(
                (unsigned long long*)(slotT + (size_t)row * KA + 1024 + colb),
                yv, __ATOMIC_RELAXED, AGENT);
        }
    };

    // ---- init barrier: all WfullT reads complete before ring overwrites it ----
    garrive(hcnt, subj);            // epoch 1 (target 16 per sub-counter)
    gwait_both(cnts, 16);

    // ---- t = 0: x-only GEMM (h=c=y=0), h_0 -> slot 0 ----
    f32x4 acc[2];
    acc[0][0] = 0.f; acc[0][1] = 0.f; acc[0][2] = 0.f; acc[0][3] = 0.f;
    acc[1][0] = 0.f; acc[1][1] = 0.f; acc[1][2] = 0.f; acc[1][3] = 0.f;
    {
        const _Float16* xb = xh + arow * 65536 + kg * 8;
        auto loadX = [&](int kk) -> f16x8 {
            return *(const f16x8*)(xb + kk * 32);
        };
        gemmPart<8>(loadX, slab, 0, rl, kg, acc);
    }
    epilogue(acc, ring);
    garrive(hcnt, subj);            // h_0 announced (epoch 2)

    // ---- pipelined steady loop ----
    for (int t = 0; t < TSTEPS; ++t) {
        // ring-wrap staleness fence (reuse distance = 16 slots)
        if ((t & 15) == 0)
            __builtin_amdgcn_fence(__ATOMIC_ACQUIRE, "agent");

        _Float16* slotT = ring + (size_t)(t & (RSLOTS - 1)) * SLOTE;

        acc[0][0] = 0.f; acc[0][1] = 0.f; acc[0][2] = 0.f; acc[0][3] = 0.f;
        acc[1][0] = 0.f; acc[1][1] = 0.f; acc[1][2] = 0.f; acc[1][3] = 0.f;

        if (t < TSTEPS - 1) {   // xGEMM(t+1) — hides h_t flag propagation
            const _Float16* xb = xh + arow * 65536 + (size_t)(t + 1) * 256 + kg * 8;
            auto loadX = [&](int kk) -> f16x8 {
                return *(const f16x8*)(xb + kk * 32);
            };
            gemmPart<8>(loadX, slab, 0, rl, kg, acc);
        }

        // preload phase-B Wd fragments from LDS (R7 indexing; used by w<4)
        f16x8 wa[8];
#pragma unroll
        for (int it = 0; it < 8; ++it) {
            int kb = ((w & 3) << 5) + it * 4 + kg;
            wa[it] = *(const f16x8*)(wdt + ((size_t)rl * 128 + (kb ^ (rl & 7))) * 8);
        }

        gwait(hcnt, (t + 2) * 16);          // h_t visible group-wide
        phaseB(t, slotT, wa);               // y_t -> out + ring

        if (t < TSTEPS - 1) {
            garrive(ycnt, subj);            // y_t announced (epoch t+1)

            {   // hGEMM(t+1) reading h_t — hides y_t propagation
                const _Float16* hb = slotT + arow * KA + kg * 8;
                auto loadH = [&](int kk) -> f16x8 {
                    return *(const f16x8*)(hb + kk * 32);
                };
                gemmPart<32>(loadH, slab, 32, rl, kg, acc);
            }

            gwait(ycnt, (t + 1) * 16);      // y_t visible group-wide

            {   // yGEMM(t+1)
                const _Float16* yb = slotT + arow * KA + 1024 + kg * 8;
                auto loadY = [&](int kk) -> f16x8 {
                    return *(const f16x8*)(yb + kk * 32);
                };
                gemmPart<8>(loadY, slab, 160, rl, kg, acc);
            }

            epilogue(acc, ring + (size_t)((t + 1) & (RSLOTS - 1)) * SLOTE);
            garrive(hcnt, subj);            // h_{t+1} announced (epoch t+3)
        }
    }
}

extern "C" void kernel_launch(void* const* d_in, const int* in_sizes, int n_in,
                              void* d_out, int out_size, void* d_ws, size_t ws_size,
                              hipStream_t stream) {
    const float* x  = (const float*)d_in[0];
    const float* Wx = (const float*)d_in[1];
    const float* Wh = (const float*)d_in[2];
    const float* b  = (const float*)d_in[3];
    const float* Wd = (const float*)d_in[4];
    const float* bd = (const float*)d_in[5];
    float* out = (float*)d_out;
    char* ws = (char*)d_ws;
    if (ws_size < WS_NEEDED) return;

    _Float16* WfullT = (_Float16*)(ws + WFULLT_OFF);
    _Float16* WdT    = (_Float16*)(ws + WDT_OFF);
    _Float16* xh     = (_Float16*)(ws + XH_OFF);
    _Float16* ring   = (_Float16*)(ws + RING_OFF);
    int*      cnts   = (int*)(ws + CNT_OFF);

    static int lds_set = 0;
    if (!lds_set) {
        hipFuncSetAttribute((const void*)lstm_persist,
                            hipFuncAttributeMaxDynamicSharedMemorySize, LDS_TOTAL);
        lds_set = 1;
    }

    prep_w<<<4352, 256, 0, stream>>>(Wx, Wh, Wd, WfullT, WdT);
    prep_x<<<8192, 256, 0, stream>>>(x, xh, cnts);
    lstm_persist<<<NBLK, 512, LDS_TOTAL, stream>>>(WfullT, WdT, xh, b, bd, ring, cnts, out);
}